// Round 8
// baseline (7169.035 us; speedup 1.0000x reference)
//
#include <hip/hip_runtime.h>
#include <hip/hip_bf16.h>
#include <math.h>
#include <stdint.h>

#define NN 6000
#define NE 96000
#define KDIN 3000
#define NCAND 12            // candidates per 128-col tile
#define NTILE 47
#define TCAND (NCAND*NTILE) // 564 per row

// output element offsets (d_out is FLOAT32)
#define OFF_ZOUT 0
#define OFF_DE1  1536000
#define OFF_Q    19536000
#define OFF_FEAT 19596000
#define OFF_DE2  20364000
#define OFF_X1   38364000
#define OFF_ATT  52188000

// totally-ordered encode of double for unsigned atomicMax
__device__ __forceinline__ unsigned long long dencode(double v){
  unsigned long long b = (unsigned long long)__double_as_longlong(v);
  return (b & 0x8000000000000000ULL) ? ~b : (b | 0x8000000000000000ULL);
}
__device__ __forceinline__ double ddecode(unsigned long long u){
  unsigned long long b = (u & 0x8000000000000000ULL) ? (u & 0x7FFFFFFFFFFFFFFFULL) : ~u;
  return __longlong_as_double((long long)b);
}

// ---------------- weight prep: transpose, cast to f64 -----------------------
__global__ void prep_k(const float* __restrict__ W1, const float* __restrict__ W2,
                       const float* __restrict__ Wq, const float* __restrict__ Wk,
                       const float* __restrict__ Wv, const float* __restrict__ Ws,
                       const float* __restrict__ bq, const float* __restrict__ bk,
                       const float* __restrict__ bv, const float* __restrict__ bs,
                       const float* __restrict__ decW, const float* __restrict__ spat,
                       double* __restrict__ W1t, double* __restrict__ W2t,
                       double* __restrict__ Bct, float* __restrict__ Dt,
                       double* __restrict__ bcat,
                       double* __restrict__ sx64, double* __restrict__ sy64,
                       double* __restrict__ ssq64,
                       float* __restrict__ sx32, float* __restrict__ sy32)
{
  int t = blockIdx.x * 256 + threadIdx.x;
  // W1 [3000][256] -> [256][3000] f64
  if (t < 768000){
    int n = t / 3000, k = t % 3000;
    W1t[t] = (double)W1[(size_t)k * 256 + n]; return;
  }
  t -= 768000;
  // W2 [256][128] -> [128][256] f64
  if (t < 32768){
    int n = t / 256, k = t % 256;
    W2t[t] = (double)W2[(size_t)k * 128 + n]; return;
  }
  t -= 32768;
  // conv weights: Bct [3][512][128] f64
  if (t < 196608){
    int l = t / 65536; int rem = t % 65536;
    int n = rem / 128, k = rem % 128;
    int sel = n >> 7, nn = n & 127;
    const float* Wm = sel==0 ? Wq : sel==1 ? Wk : sel==2 ? Wv : Ws;
    Bct[t] = (double)Wm[((size_t)(l*128) + k) * 128 + nn]; return;
  }
  t -= 196608;
  // decW [256][3000] -> [3000][256] f32 (decoder stays f32)
  if (t < 768000){
    int n = t / 256, k = t % 256;
    Dt[t] = decW[(size_t)k * 3000 + n]; return;
  }
  t -= 768000;
  if (t < 1536){
    int l = t / 512, n = t % 512;
    int sel = n >> 7, nn = n & 127;
    const float* bm = sel==0 ? bq : sel==1 ? bk : sel==2 ? bv : bs;
    bcat[t] = (double)bm[l*128 + nn]; return;
  }
  t -= 1536;
  if (t < NN){
    float sx = spat[(size_t)t*2], sy = spat[(size_t)t*2+1];
    sx64[t]=(double)sx; sy64[t]=(double)sy;
    ssq64[t]=(double)sx*(double)sx + (double)sy*(double)sy;
    sx32[t]=sx; sy32[t]=sy; return;
  }
}

// ---------------- f64 vector GEMM, NT layout, 64x64 tile --------------------
// C = A(TA,[M][K],lda) @ Bt(f64,[N][K],ldb)^T
// EPI 0: out = acc + bias; EPI 1: out = elu((acc+bias)*gam*BNS + bet)
template<int EPI, typename TA>
__global__ __launch_bounds__(256)
void gemm64_k(const TA* __restrict__ A, int lda,
              const double* __restrict__ Bt, int ldb,
              int M, int K, int Ncol,
              double* __restrict__ outF, int ldc,
              const double* __restrict__ bias,
              const float* __restrict__ gam, const float* __restrict__ bet)
{
  __shared__ double lA[64][33];
  __shared__ double lB[64][33];
  const int tid = threadIdx.x;
  const int m0 = blockIdx.y * 64;
  const int n0 = blockIdx.x * 64;
  const int tx = tid & 15;
  const int ty = tid >> 4;

  double acc[4][4];
  #pragma unroll
  for (int i=0;i<4;i++)
    #pragma unroll
    for (int j=0;j<4;j++) acc[i][j] = 0.0;

  const int nkt = (K + 31) >> 5;
  for (int kt = 0; kt < nkt; kt++){
    const int k0 = kt << 5;
    __syncthreads();
    #pragma unroll
    for (int c=0;c<8;c++){
      int lin = tid + c*256;
      int row = lin >> 5, col = lin & 31;
      int gm = m0 + row, gk = k0 + col;
      double va = 0.0, vb = 0.0;
      if (gm < M && gk < K)        va = (double)A [(size_t)gm*lda + gk];
      if (n0+row < Ncol && gk < K) vb = Bt[(size_t)(n0+row)*ldb + gk];
      lA[row][col] = va;
      lB[row][col] = vb;
    }
    __syncthreads();
    #pragma unroll 2
    for (int kk=0; kk<32; kk++){
      double a0=lA[ty*4+0][kk], a1=lA[ty*4+1][kk], a2=lA[ty*4+2][kk], a3=lA[ty*4+3][kk];
      double b0=lB[tx*4+0][kk], b1=lB[tx*4+1][kk], b2=lB[tx*4+2][kk], b3=lB[tx*4+3][kk];
      acc[0][0]+=a0*b0; acc[0][1]+=a0*b1; acc[0][2]+=a0*b2; acc[0][3]+=a0*b3;
      acc[1][0]+=a1*b0; acc[1][1]+=a1*b1; acc[1][2]+=a1*b2; acc[1][3]+=a1*b3;
      acc[2][0]+=a2*b0; acc[2][1]+=a2*b1; acc[2][2]+=a2*b2; acc[2][3]+=a2*b3;
      acc[3][0]+=a3*b0; acc[3][1]+=a3*b1; acc[3][2]+=a3*b2; acc[3][3]+=a3*b3;
    }
  }
  const double BNS = 0.99995000374968755261; // 1/sqrt(1+1e-4)
  #pragma unroll
  for (int j=0;j<4;j++){
    int gn = n0 + tx*4 + j;
    if (gn >= Ncol) continue;
    double bi = bias[gn];
    double gs = 0.0, be = 0.0;
    if (EPI >= 1){ gs = (double)gam[gn]*BNS; be = (double)bet[gn]; }
    #pragma unroll
    for (int i=0;i<4;i++){
      int gm = m0 + ty*4 + i;
      if (gm >= M) continue;
      double v = acc[i][j] + bi;
      if (EPI >= 1){ v = v*gs + be; v = v > 0.0 ? v : expm1(v); }
      outF[(size_t)gm*ldc + gn] = v;
    }
  }
}

// ---------------- f32 GEMM (decoder only, EPI2: elu-bn to two f32 outs) -----
__global__ __launch_bounds__(256)
void gemm32d_k(const float* __restrict__ A, int lda,
               const float* __restrict__ Bt, int ldb,
               int M, int K, int Ncol,
               float* __restrict__ out1, int ldc,
               const float* __restrict__ bias, const float* __restrict__ gam,
               const float* __restrict__ bet, float* __restrict__ out2)
{
  __shared__ float lA[64][33];
  __shared__ float lB[64][33];
  const int tid = threadIdx.x;
  const int m0 = blockIdx.y * 64;
  const int n0 = blockIdx.x * 64;
  const int tx = tid & 15;
  const int ty = tid >> 4;

  float acc[4][4];
  #pragma unroll
  for (int i=0;i<4;i++)
    #pragma unroll
    for (int j=0;j<4;j++) acc[i][j] = 0.f;

  const int nkt = (K + 31) >> 5;
  for (int kt = 0; kt < nkt; kt++){
    const int k0 = kt << 5;
    __syncthreads();
    #pragma unroll
    for (int c=0;c<8;c++){
      int lin = tid + c*256;
      int row = lin >> 5, col = lin & 31;
      int gm = m0 + row, gk = k0 + col;
      float va = 0.f, vb = 0.f;
      if (gm < M && gk < K)        va = A [(size_t)gm*lda + gk];
      if (n0+row < Ncol && gk < K) vb = Bt[(size_t)(n0+row)*ldb + gk];
      lA[row][col] = va;
      lB[row][col] = vb;
    }
    __syncthreads();
    #pragma unroll 4
    for (int kk=0; kk<32; kk++){
      float a0=lA[ty*4+0][kk], a1=lA[ty*4+1][kk], a2=lA[ty*4+2][kk], a3=lA[ty*4+3][kk];
      float b0=lB[tx*4+0][kk], b1=lB[tx*4+1][kk], b2=lB[tx*4+2][kk], b3=lB[tx*4+3][kk];
      acc[0][0]+=a0*b0; acc[0][1]+=a0*b1; acc[0][2]+=a0*b2; acc[0][3]+=a0*b3;
      acc[1][0]+=a1*b0; acc[1][1]+=a1*b1; acc[1][2]+=a1*b2; acc[1][3]+=a1*b3;
      acc[2][0]+=a2*b0; acc[2][1]+=a2*b1; acc[2][2]+=a2*b2; acc[2][3]+=a2*b3;
      acc[3][0]+=a3*b0; acc[3][1]+=a3*b1; acc[3][2]+=a3*b2; acc[3][3]+=a3*b3;
    }
  }
  const float BNS = 0.99995000374968755f;
  #pragma unroll
  for (int j=0;j<4;j++){
    int gn = n0 + tx*4 + j;
    if (gn >= Ncol) continue;
    float bi = bias[gn];
    float gs = gam[gn]*BNS, be = bet[gn];
    #pragma unroll
    for (int i=0;i<4;i++){
      int gm = m0 + ty*4 + i;
      if (gm >= M) continue;
      float v = acc[i][j] + bi;
      v = v*gs + be; v = v > 0.f ? v : expm1f(v);
      out1[(size_t)gm*ldc + gn] = v;
      out2[(size_t)gm*ldc + gn] = v;
    }
  }
}

// ---------------- f32 distance GEMM + fused per-tile top-12 -----------------
__global__ __launch_bounds__(256)
void dist32_k(const float* __restrict__ Z, const float* __restrict__ Znb,
              const float* __restrict__ sxA, const float* __restrict__ syA, const float* __restrict__ cjA,
              float* __restrict__ candV, int* __restrict__ candI)
{
  __shared__ __align__(16) char smem[34560];
  float (*lA)[33]    = (float(*)[33])(smem);
  float (*lB)[33]    = (float(*)[33])(smem + 8448);
  float (*stile)[129]= (float(*)[129])(smem);
  float* sSx = (float*)(smem + 33024);
  float* sSy = sSx + 128;
  float* sC  = sSy + 128;

  const int tid = threadIdx.x;
  const int m0 = blockIdx.y * 64;
  const int n0 = blockIdx.x * 128;
  const int tx = tid & 15;
  const int ty = tid >> 4;

  if (tid < 128){
    int jg = n0 + tid;
    if (jg < NN){ sSx[tid]=sxA[jg]; sSy[tid]=syA[jg]; sC[tid]=cjA[jg]; }
    else        { sSx[tid]=0.f; sSy[tid]=0.f; sC[tid]=-3e38f; }
  }

  float acc[4][8];
  #pragma unroll
  for (int i=0;i<4;i++)
    #pragma unroll
    for (int j=0;j<8;j++) acc[i][j] = 0.f;

  for (int kt = 0; kt < 8; kt++){
    const int k0 = kt << 5;
    __syncthreads();
    #pragma unroll
    for (int c=0;c<8;c++){
      int lin = tid + c*256;
      int row = lin >> 5, col = lin & 31;
      int gm = m0 + row;
      lA[row][col] = (gm < NN) ? Z[(size_t)gm*256 + k0 + col] : 0.f;
    }
    #pragma unroll
    for (int c=0;c<16;c++){
      int lin = tid + c*256;
      int row = lin >> 5, col = lin & 31;
      int gn = n0 + row;
      lB[row][col] = (gn < NN) ? Znb[(size_t)gn*256 + k0 + col] : 0.f;
    }
    __syncthreads();
    #pragma unroll 4
    for (int kk=0; kk<32; kk++){
      float a[4], b[8];
      #pragma unroll
      for (int i=0;i<4;i++) a[i] = lA[ty*4+i][kk];
      #pragma unroll
      for (int j=0;j<8;j++) b[j] = lB[tx*8+j][kk];
      #pragma unroll
      for (int i=0;i<4;i++)
        #pragma unroll
        for (int j=0;j<8;j++) acc[i][j] += a[i]*b[j];
    }
  }

  __syncthreads();
  #pragma unroll
  for (int i=0;i<4;i++)
    #pragma unroll
    for (int j=0;j<8;j++)
      stile[ty*4+i][tx*8+j] = acc[i][j];
  __syncthreads();

  if (tid < 64){
    const int gi = m0 + tid;
    if (gi < NN){
      float sxi = sxA[gi], syi = syA[gi];
      float tv[NCAND]; int ti[NCAND];
      #pragma unroll
      for (int p=0;p<NCAND;p++){ tv[p] = -3.4e38f; ti[p] = -1; }
      #pragma unroll 1
      for (int jj=0; jj<128; jj++){
        float s = 2.f*stile[tid][jj] + 2.f*(sxi*sSx[jj] + syi*sSy[jj]) + sC[jj];
        if (s > tv[NCAND-1]){
          bool g[NCAND];
          #pragma unroll
          for (int p=0;p<NCAND;p++) g[p] = s > tv[p];
          #pragma unroll
          for (int p=NCAND-1;p>0;--p) if (g[p-1]){ tv[p]=tv[p-1]; ti[p]=ti[p-1]; }
          #pragma unroll
          for (int p=0;p<NCAND;p++){ bool pl = g[p] && (p==0 || !g[p-1]); if (pl){ tv[p]=s; ti[p]=n0+jj; } }
        }
      }
      size_t base = ((size_t)gi*NTILE + blockIdx.x)*NCAND;
      #pragma unroll
      for (int p=0;p<NCAND;p++){ candV[base+p]=tv[p]; candI[base+p]=ti[p]; }
    }
  }
}

// ---------------- merge: f64 rescore from f64 z, top-9, softmax -------------
__global__ __launch_bounds__(256)
void merge64_k(const float* __restrict__ candV, const int* __restrict__ candI,
               const double* __restrict__ Z, const double* __restrict__ Znb,
               const double* __restrict__ sx64, const double* __restrict__ sy64,
               double* __restrict__ wgt9, int* __restrict__ idx9)
{
  __shared__ double zi[256];
  __shared__ double sval[TCAND];
  __shared__ int    sidx[TCAND];
  const int i = blockIdx.x;
  const int t = threadIdx.x;
  zi[t] = Z[(size_t)i*256 + t];
  __syncthreads();
  const double sxi = sx64[i], syi = sy64[i];
  for (int c = t; c < TCAND; c += 256){
    float fv = candV[(size_t)i*TCAND + c];
    int j = candI[(size_t)i*TCAND + c];
    double s = -1.0e300;
    if (fv > -1e37f && j >= 0 && j < NN){
      const double* zj = Znb + (size_t)j*256;
      double dot = 0.0, zz = 0.0;
      #pragma unroll 4
      for (int c2=0;c2<256;c2++){
        double a = zi[c2], b = zj[c2];
        dot += a*b; zz += b*b;
      }
      double sxj = sx64[j], syj = sy64[j];
      s = 2.0*dot + 2.0*(sxi*sxj + syi*syj) - zz - (sxj*sxj + syj*syj);
    }
    sval[c] = s; sidx[c] = j;
  }
  __syncthreads();
  if (t == 0){
    double tv[9]; int ti[9];
    #pragma unroll
    for (int p=0;p<9;p++){ tv[p]=-1.0e301; ti[p]=0; }
    for (int c=0;c<TCAND;c++){
      double s = sval[c];
      if (s < -1.0e299 || !(s > tv[8])) continue;
      int j = sidx[c];
      bool g[9];
      #pragma unroll
      for (int p=0;p<9;p++) g[p] = s > tv[p];
      #pragma unroll
      for (int p=8;p>0;--p) if (g[p-1]){ tv[p]=tv[p-1]; ti[p]=ti[p-1]; }
      #pragma unroll
      for (int p=0;p<9;p++){ bool pl = g[p] && (p==0 || !g[p-1]); if (pl){ tv[p]=s; ti[p]=j; } }
    }
    double m = tv[0], e[9], S=0.0;
    #pragma unroll
    for (int k=0;k<9;k++){ e[k]=exp(tv[k]-m); S+=e[k]; }
    #pragma unroll
    for (int k=0;k<9;k++){
      wgt9[(size_t)i*9+k] = e[k]/S;
      idx9[(size_t)i*9+k] = ti[k];
    }
  }
}

// ---------------- znb prep: cj = -(|z|^2+ssq) (f32, for candidates) --------
__global__ __launch_bounds__(256)
void znbprep_k(const double* __restrict__ znb, const double* __restrict__ ssq64,
               float* __restrict__ cjA)
{
  __shared__ double red[256];
  int i = blockIdx.x, d = threadIdx.x;
  double v = znb[(size_t)i*256 + d];
  red[d] = v*v;
  __syncthreads();
  for (int s=128; s; s>>=1){ if (d<s) red[d]+=red[d+s]; __syncthreads(); }
  if (d==0) cjA[i] = -(float)(red[0] + ssq64[i]);
}

// ---------------- edge pipeline (f64) ----------------------------------------
__global__ void seginit_k(unsigned long long* __restrict__ smaxU, double* __restrict__ ssum){
  int t = blockIdx.x*256+threadIdx.x;
  if (t < NN){ smaxU[t] = 0ULL; ssum[t] = 0.0; }
}

__global__ __launch_bounds__(256)
void edge_logit_k(const double* __restrict__ QKVS, const int* __restrict__ src,
                  const int* __restrict__ dst, double* __restrict__ elog,
                  unsigned long long* __restrict__ smaxU)
{
  int e = blockIdx.x*4 + (threadIdx.x>>6);
  if (e >= NE) return;
  int lane = threadIdx.x & 63;
  int s = src[e], d = dst[e];
  const double* q = QKVS + (size_t)d*512;
  const double* k = QKVS + (size_t)s*512 + 128;
  double p = q[lane]*k[lane] + q[lane+64]*k[lane+64];
  #pragma unroll
  for (int off=32; off; off>>=1) p += __shfl_down(p, off);
  if (lane == 0){
    double lg = p * 0.088388347648318447; // 1/sqrt(128)
    elog[e] = lg;
    atomicMax(&smaxU[d], dencode(lg));
  }
}

__global__ void edge_expsum_k(const int* __restrict__ dst, double* __restrict__ elog,
                              const unsigned long long* __restrict__ smaxU, double* __restrict__ ssum){
  int e = blockIdx.x*256+threadIdx.x;
  if (e >= NE) return;
  int d = dst[e];
  double v = exp(elog[e] - ddecode(smaxU[d]));
  elog[e] = v;
  atomicAdd(&ssum[d], v);
}

__global__ __launch_bounds__(256)
void edge_aggr_k(double* __restrict__ QKVS, const int* __restrict__ src,
                 const int* __restrict__ dst, double* __restrict__ elog, const double* __restrict__ ssum)
{
  int e = blockIdx.x*4 + (threadIdx.x>>6);
  if (e >= NE) return;
  int lane = threadIdx.x & 63;
  int s = src[e], d = dst[e];
  double a = elog[e] / ssum[d];
  const double* v = QKVS + (size_t)s*512 + 256;
  double* o = QKVS + (size_t)d*512 + 384;
  atomicAdd(&o[lane], a*v[lane]);
  atomicAdd(&o[lane+64], a*v[lane+64]);
  if (lane == 0) elog[e] = a;
}

__global__ __launch_bounds__(256)
void spmm_k(const int* __restrict__ src, const int* __restrict__ dst,
            const double* __restrict__ alpha, const double* __restrict__ QKVS, double* __restrict__ hnew)
{
  int e = blockIdx.x*4 + (threadIdx.x>>6);
  if (e >= NE) return;
  int lane = threadIdx.x & 63;
  int s = src[e], d = dst[e];
  if (s == d) return;
  double a = 0.5 * alpha[e];
  const double* o = QKVS + (size_t)d*512 + 384;
  double* h = hnew + (size_t)s*128;
  atomicAdd(&h[lane], a*o[lane]);
  atomicAdd(&h[lane+64], a*o[lane+64]);
}

__global__ void att_scatter_k(const int* __restrict__ src, const int* __restrict__ dst,
                              const double* __restrict__ alpha, float* __restrict__ att)
{
  int e = blockIdx.x*256 + threadIdx.x;
  if (e >= NE) return;
  int s = src[e], d = dst[e];
  if (s == d) return;
  atomicAdd(&att[(size_t)s*NN + d], (float)alpha[e]);
}

// ---------------- small elementwise kernels ---------------------------------
__global__ void relu_k(const double* __restrict__ a, double* __restrict__ b){
  int t = blockIdx.x*256+threadIdx.x;
  if (t < NN*128) b[t] = fmax(a[t], 0.0);
}
__global__ void copymu_k(const double* __restrict__ hn, double* __restrict__ z){
  int t = blockIdx.x*256+threadIdx.x;
  if (t < NN*128){ int i=t>>7, d=t&127; z[(size_t)i*256 + 128 + d] = hn[t]; }
}
__global__ void castz_k(const double* __restrict__ z64, float* __restrict__ z32, int n){
  int t = blockIdx.x*256+threadIdx.x;
  if (t < n) z32[t] = (float)z64[t];
}
__global__ void featout_k(const double* __restrict__ z, float* __restrict__ o){
  int t = blockIdx.x*256+threadIdx.x;
  if (t < NN*128){ int i=t>>7, d=t&127; o[t] = (float)z[(size_t)i*256 + d]; }
}

__global__ __launch_bounds__(256)
void zout_k(const double* __restrict__ Z, const double* __restrict__ Znb,
            const int* __restrict__ idx9, const double* __restrict__ wgt9,
            float* __restrict__ zoOut, float* __restrict__ zoF32, float* __restrict__ x1)
{
  int i = blockIdx.x; int d = threadIdx.x;
  double a = Z[(size_t)i*256 + d];
  #pragma unroll
  for (int k=0;k<9;k++){
    int j = idx9[(size_t)i*9+k];
    double w = wgt9[(size_t)i*9+k];
    double t = w * Znb[(size_t)j*256 + d];
    a += t;
    x1[((size_t)i*9+k)*256 + d] = (float)t;
  }
  float af = (float)a;
  zoOut[(size_t)i*256+d] = af;
  zoF32[(size_t)i*256+d] = af;
}

__global__ __launch_bounds__(256)
void q_k(const float* __restrict__ zoF, const float* __restrict__ clus, float* __restrict__ qB)
{
  __shared__ float wred[10][4];
  __shared__ float qs[10];
  int i = blockIdx.x, d = threadIdx.x;
  int lane = d & 63, wv = d >> 6;
  float zo = zoF[(size_t)i*256 + d];
  #pragma unroll
  for (int c=0;c<10;c++){
    float df = zo - clus[(size_t)c*256 + d];
    float p = df*df;
    #pragma unroll
    for (int off=32; off; off>>=1) p += __shfl_down(p, off);
    if (lane == 0) wred[c][wv] = p;
  }
  __syncthreads();
  if (d < 10){
    float d2 = wred[d][0]+wred[d][1]+wred[d][2]+wred[d][3];
    qs[d] = 1.f/(1.f + d2);
  }
  __syncthreads();
  if (d < 10){
    float s = 0.f;
    #pragma unroll
    for (int c=0;c<10;c++) s += qs[c];
    qB[(size_t)i*10 + d] = qs[d]/s;
  }
}

// ---------------- host ------------------------------------------------------
extern "C" void kernel_launch(void* const* d_in, const int* in_sizes, int n_in,
                              void* d_out, int out_size, void* d_ws, size_t ws_size,
                              hipStream_t stream)
{
  (void)in_sizes; (void)n_in; (void)out_size; (void)ws_size;
  const float* x    = (const float*)d_in[0];
  const float* xnb  = (const float*)d_in[1];
  const float* spat = (const float*)d_in[2];
  const int*   adj  = (const int*)d_in[3];
  const int*   adjp = (const int*)d_in[4];
  const float* W1   = (const float*)d_in[5];
  const float* b1   = (const float*)d_in[6];
  const float* g1   = (const float*)d_in[7];
  const float* be1  = (const float*)d_in[8];
  const float* W2   = (const float*)d_in[9];
  const float* b2   = (const float*)d_in[10];
  const float* g2   = (const float*)d_in[11];
  const float* be2  = (const float*)d_in[12];
  const float* Wq   = (const float*)d_in[13];
  const float* Wk   = (const float*)d_in[14];
  const float* Wv   = (const float*)d_in[15];
  const float* Wsm  = (const float*)d_in[16];
  const float* bq   = (const float*)d_in[17];
  const float* bk   = (const float*)d_in[18];
  const float* bv   = (const float*)d_in[19];
  const float* bs   = (const float*)d_in[20];
  const float* decW = (const float*)d_in[21];
  const float* decb = (const float*)d_in[22];
  const float* decg = (const float*)d_in[23];
  const float* decbe= (const float*)d_in[24];
  const float* clus = (const float*)d_in[25];
  float* outF = (float*)d_out;
  const int* srcA = adj,  *dstA = adj + NE;
  const int* srcP = adjp, *dstP = adjp + NE;

  char* wsb = (char*)d_ws;
  size_t off = 0;
  auto alloc = [&](size_t bytes)->char*{
    char* p = wsb + off;
    off = (off + bytes + 255) & ~(size_t)255;
    return p;
  };
  double* b1d   = (double*)alloc(256*8);        // cast biases on device? keep f64 copies below
  (void)b1d; off = 0;                            // reset; do explicit layout

  double* W1t  = (double*)alloc(768000*8);
  double* W2t  = (double*)alloc(32768*8);
  double* Bct  = (double*)alloc(196608*8);
  float*  Dt   = (float*) alloc(768000*4);
  double* bcat = (double*)alloc(1536*8);
  double* sx64 = (double*)alloc(NN*8);
  double* sy64 = (double*)alloc(NN*8);
  double* ssq64= (double*)alloc(NN*8);
  float*  sx32 = (float*) alloc(NN*4);
  float*  sy32 = (float*) alloc(NN*4);
  double* b1c  = (double*)alloc(256*8);
  double* b2c  = (double*)alloc(128*8);
  double* H1   = (double*)alloc((size_t)NN*256*8);
  double* zX64 = (double*)alloc((size_t)NN*256*8);
  double* zNB64= (double*)alloc((size_t)NN*256*8);
  double* hcur = (double*)alloc((size_t)NN*128*8);
  double* hnew = (double*)alloc((size_t)NN*128*8);
  double* QK1  = (double*)alloc((size_t)NN*512*8);
  double* QK2  = (double*)alloc((size_t)NN*512*8);
  double* alphaA=(double*)alloc((size_t)NE*8);
  double* alphaP=(double*)alloc((size_t)NE*8);
  unsigned long long* smaxU = (unsigned long long*)alloc(NN*8);
  double* ssum = (double*)alloc(NN*8);
  float*  zX32 = (float*) alloc((size_t)NN*256*4);
  float*  zNB32= (float*) alloc((size_t)NN*256*4);
  float*  cjA  = (float*) alloc(NN*4);
  float*  candV= (float*) alloc((size_t)NN*TCAND*4);
  int*    candI= (int*)   alloc((size_t)NN*TCAND*4);
  int*    idx9 = (int*)   alloc((size_t)NN*9*4);
  double* wgt9 = (double*)alloc((size_t)NN*9*8);
  float*  zoF32= (float*) alloc((size_t)NN*256*4);

  // b1/b2 f64 copies via tiny kernel folded into prep grid: reuse castz-like path
  // (simpler: dedicated small kernel)
  {
    struct B { const float* s; double* d; int n; };
    // cast b1 (256) and b2 (128) — do with one castup kernel each
  }
  // cast biases using a lambda kernel is not possible; use castz-like kernels below.

  prep_k<<<6926, 256, 0, stream>>>(W1, W2, Wq, Wk, Wv, Wsm, bq, bk, bv, bs, decW, spat,
                                   W1t, W2t, Bct, Dt, bcat,
                                   sx64, sy64, ssq64, sx32, sy32);
  // f64 copies of encoder biases
  {
    // small one-off kernels
    auto castup = [&](const float* s, double* d, int n){
      // use castz_k in reverse? write a tiny kernel inline is impossible; use hip lambda-less approach:
      // reuse copy via gemm bias path is messy — dedicated kernel below.
      (void)s; (void)d; (void)n;
    };
    (void)castup;
  }
  // dedicated kernels for bias casts
  {
    extern __global__ void castup_k(const float*, double*, int);
  }
  // (declared below; launched here)
  void castup_launch(const float*, double*, int, hipStream_t);
  castup_launch(b1, b1c, 256, stream);
  castup_launch(b2, b2c, 128, stream);

  auto enc = [&](const float* xin, double* zbuf, bool isX){
    gemm64_k<1,float><<<dim3(4,94), 256, 0, stream>>>(xin, KDIN, W1t, KDIN, NN, KDIN, 256,
                                                      H1, 256, b1c, g1, be1);
    gemm64_k<1,double><<<dim3(2,94), 256, 0, stream>>>(H1, 256, W2t, 256, NN, 256, 128,
                                                       zbuf, 256, b2c, g2, be2);
    const double* hin = zbuf; int ldh = 256;
    for (int l=0; l<3; l++){
      const double* Bh = Bct + (size_t)l*65536;
      const double* bc = bcat + l*512;
      gemm64_k<0,double><<<dim3(8,94), 256, 0, stream>>>(hin, ldh, Bh, 128, NN, 128, 512,
                                                         QK1, 512, bc, nullptr, nullptr);
      seginit_k<<<24, 256, 0, stream>>>(smaxU, ssum);
      edge_logit_k<<<24000, 256, 0, stream>>>(QK1, srcA, dstA, alphaA, smaxU);
      edge_expsum_k<<<375, 256, 0, stream>>>(dstA, alphaA, smaxU, ssum);
      edge_aggr_k<<<24000, 256, 0, stream>>>(QK1, srcA, dstA, alphaA, ssum);

      const double* hin2 = (l==1) ? (QK1 + 384) : hin;
      int ldh2 = (l==1) ? 512 : ldh;
      gemm64_k<0,double><<<dim3(8,94), 256, 0, stream>>>(hin2, ldh2, Bh, 128, NN, 128, 512,
                                                         QK2, 512, bc, nullptr, nullptr);
      seginit_k<<<24, 256, 0, stream>>>(smaxU, ssum);
      edge_logit_k<<<24000, 256, 0, stream>>>(QK2, srcP, dstP, alphaP, smaxU);
      edge_expsum_k<<<375, 256, 0, stream>>>(dstP, alphaP, smaxU, ssum);
      edge_aggr_k<<<24000, 256, 0, stream>>>(QK2, srcP, dstP, alphaP, ssum);

      if (isX && l == 2){
        hipMemsetAsync(outF + (size_t)OFF_ATT, 0, (size_t)NN*NN*4, stream);
        att_scatter_k<<<375, 256, 0, stream>>>(srcP, dstP, alphaP, outF + (size_t)OFF_ATT);
      }
      hipMemsetAsync(hnew, 0, (size_t)NN*128*8, stream);
      spmm_k<<<24000, 256, 0, stream>>>(srcA, dstA, alphaA, QK1, hnew);
      spmm_k<<<24000, 256, 0, stream>>>(srcP, dstP, alphaP, QK2, hnew);
      if (l < 2){
        relu_k<<<3000, 256, 0, stream>>>(hnew, hcur);
        hin = hcur; ldh = 128;
      } else {
        copymu_k<<<3000, 256, 0, stream>>>(hnew, zbuf);
      }
    }
  };
  enc(x,   zX64,  true);
  enc(xnb, zNB64, false);

  castz_k<<<6000, 256, 0, stream>>>(zX64,  zX32,  NN*256);
  castz_k<<<6000, 256, 0, stream>>>(zNB64, zNB32, NN*256);
  znbprep_k<<<NN, 256, 0, stream>>>(zNB64, ssq64, cjA);
  dist32_k<<<dim3(NTILE,94), 256, 0, stream>>>(zX32, zNB32, sx32, sy32, cjA, candV, candI);
  merge64_k<<<NN, 256, 0, stream>>>(candV, candI, zX64, zNB64, sx64, sy64, wgt9, idx9);

  zout_k<<<NN, 256, 0, stream>>>(zX64, zNB64, idx9, wgt9,
                                 outF + (size_t)OFF_ZOUT, zoF32, outF + (size_t)OFF_X1);
  gemm32d_k<<<dim3(47,94), 256, 0, stream>>>(zoF32, 256, Dt, 256, NN, 256, 3000,
                                             outF + (size_t)OFF_DE1, 3000, decb, decg, decbe,
                                             outF + (size_t)OFF_DE2);
  q_k<<<NN, 256, 0, stream>>>(zoF32, clus, outF + (size_t)OFF_Q);
  featout_k<<<3000, 256, 0, stream>>>(zX64, outF + (size_t)OFF_FEAT);
}

// ---------------- bias cast helper ------------------------------------------
__global__ void castup_k(const float* __restrict__ s, double* __restrict__ d, int n){
  int t = blockIdx.x*256 + threadIdx.x;
  if (t < n) d[t] = (double)s[t];
}
void castup_launch(const float* s, double* d, int n, hipStream_t stream){
  castup_k<<<(n+255)/256, 256, 0, stream>>>(s, d, n);
}

// Round 9
// 5214.698 us; speedup vs baseline: 1.3748x; 1.3748x over previous
//
#include <hip/hip_runtime.h>
#include <hip/hip_bf16.h>
#include <math.h>
#include <stdint.h>

#define NN 6000
#define NE 96000
#define KDIN 3000
#define NCAND 12            // candidates per 128-col tile
#define NTILE 47
#define TCAND (NCAND*NTILE) // 564 per row
#define PRE 32              // f64-rescored candidates per row

// output element offsets (d_out is FLOAT32)
#define OFF_ZOUT 0
#define OFF_DE1  1536000
#define OFF_Q    19536000
#define OFF_FEAT 19596000
#define OFF_DE2  20364000
#define OFF_X1   38364000
#define OFF_ATT  52188000

// ---------------- weight prep: transpose, cast to f64 -----------------------
__global__ void prep_k(const float* __restrict__ W1, const float* __restrict__ W2,
                       const float* __restrict__ Wq, const float* __restrict__ Wk,
                       const float* __restrict__ Wv, const float* __restrict__ Ws,
                       const float* __restrict__ bq, const float* __restrict__ bk,
                       const float* __restrict__ bv, const float* __restrict__ bs,
                       const float* __restrict__ decW, const float* __restrict__ spat,
                       double* __restrict__ W1t, double* __restrict__ W2t,
                       double* __restrict__ Bct, float* __restrict__ Dt,
                       double* __restrict__ bcat,
                       double* __restrict__ sx64, double* __restrict__ sy64,
                       double* __restrict__ ssq64,
                       float* __restrict__ sx32, float* __restrict__ sy32)
{
  int t = blockIdx.x * 256 + threadIdx.x;
  if (t < 768000){
    int n = t / 3000, k = t % 3000;
    W1t[t] = (double)W1[(size_t)k * 256 + n]; return;
  }
  t -= 768000;
  if (t < 32768){
    int n = t / 256, k = t % 256;
    W2t[t] = (double)W2[(size_t)k * 128 + n]; return;
  }
  t -= 32768;
  if (t < 196608){
    int l = t / 65536; int rem = t % 65536;
    int n = rem / 128, k = rem % 128;
    int sel = n >> 7, nn = n & 127;
    const float* Wm = sel==0 ? Wq : sel==1 ? Wk : sel==2 ? Wv : Ws;
    Bct[t] = (double)Wm[((size_t)(l*128) + k) * 128 + nn]; return;
  }
  t -= 196608;
  if (t < 768000){
    int n = t / 256, k = t % 256;
    Dt[t] = decW[(size_t)k * 3000 + n]; return;
  }
  t -= 768000;
  if (t < 1536){
    int l = t / 512, n = t % 512;
    int sel = n >> 7, nn = n & 127;
    const float* bm = sel==0 ? bq : sel==1 ? bk : sel==2 ? bv : bs;
    bcat[t] = (double)bm[l*128 + nn]; return;
  }
  t -= 1536;
  if (t < NN){
    float sx = spat[(size_t)t*2], sy = spat[(size_t)t*2+1];
    sx64[t]=(double)sx; sy64[t]=(double)sy;
    ssq64[t]=(double)sx*(double)sx + (double)sy*(double)sy;
    sx32[t]=sx; sy32[t]=sy; return;
  }
}

__global__ void castup_k(const float* __restrict__ s, double* __restrict__ d, int n){
  int t = blockIdx.x*256 + threadIdx.x;
  if (t < n) d[t] = (double)s[t];
}

// ---------------- f64 vector GEMM, NT layout, 64x64 tile --------------------
// EPI 0: out = acc + bias (optional dual write); EPI 1: elu-bn epilogue
template<int EPI, typename TA>
__global__ __launch_bounds__(256)
void gemm64_k(const TA* __restrict__ A, int lda,
              const double* __restrict__ Bt, int ldb,
              int M, int K, int Ncol,
              double* __restrict__ outF, int ldc,
              const double* __restrict__ bias,
              const float* __restrict__ gam, const float* __restrict__ bet,
              double* __restrict__ outF2)
{
  __shared__ double lA[64][33];
  __shared__ double lB[64][33];
  const int tid = threadIdx.x;
  const int m0 = blockIdx.y * 64;
  const int n0 = blockIdx.x * 64;
  const int tx = tid & 15;
  const int ty = tid >> 4;

  double acc[4][4];
  #pragma unroll
  for (int i=0;i<4;i++)
    #pragma unroll
    for (int j=0;j<4;j++) acc[i][j] = 0.0;

  const int nkt = (K + 31) >> 5;
  for (int kt = 0; kt < nkt; kt++){
    const int k0 = kt << 5;
    __syncthreads();
    #pragma unroll
    for (int c=0;c<8;c++){
      int lin = tid + c*256;
      int row = lin >> 5, col = lin & 31;
      int gm = m0 + row, gk = k0 + col;
      double va = 0.0, vb = 0.0;
      if (gm < M && gk < K)        va = (double)A [(size_t)gm*lda + gk];
      if (n0+row < Ncol && gk < K) vb = Bt[(size_t)(n0+row)*ldb + gk];
      lA[row][col] = va;
      lB[row][col] = vb;
    }
    __syncthreads();
    #pragma unroll 2
    for (int kk=0; kk<32; kk++){
      double a0=lA[ty*4+0][kk], a1=lA[ty*4+1][kk], a2=lA[ty*4+2][kk], a3=lA[ty*4+3][kk];
      double b0=lB[tx*4+0][kk], b1=lB[tx*4+1][kk], b2=lB[tx*4+2][kk], b3=lB[tx*4+3][kk];
      acc[0][0]+=a0*b0; acc[0][1]+=a0*b1; acc[0][2]+=a0*b2; acc[0][3]+=a0*b3;
      acc[1][0]+=a1*b0; acc[1][1]+=a1*b1; acc[1][2]+=a1*b2; acc[1][3]+=a1*b3;
      acc[2][0]+=a2*b0; acc[2][1]+=a2*b1; acc[2][2]+=a2*b2; acc[2][3]+=a2*b3;
      acc[3][0]+=a3*b0; acc[3][1]+=a3*b1; acc[3][2]+=a3*b2; acc[3][3]+=a3*b3;
    }
  }
  const double BNS = 0.99995000374968755261; // 1/sqrt(1+1e-4)
  #pragma unroll
  for (int j=0;j<4;j++){
    int gn = n0 + tx*4 + j;
    if (gn >= Ncol) continue;
    double bi = bias[gn];
    double gs = 0.0, be = 0.0;
    if (EPI >= 1){ gs = (double)gam[gn]*BNS; be = (double)bet[gn]; }
    #pragma unroll
    for (int i=0;i<4;i++){
      int gm = m0 + ty*4 + i;
      if (gm >= M) continue;
      double v = acc[i][j] + bi;
      if (EPI >= 1){ v = v*gs + be; v = v > 0.0 ? v : expm1(v); }
      outF[(size_t)gm*ldc + gn] = v;
      if (outF2) outF2[(size_t)gm*ldc + gn] = v;
    }
  }
}

// ---------------- f32 GEMM (decoder, elu-bn to two f32 outs) ----------------
__global__ __launch_bounds__(256)
void gemm32d_k(const float* __restrict__ A, int lda,
               const float* __restrict__ Bt, int ldb,
               int M, int K, int Ncol,
               float* __restrict__ out1, int ldc,
               const float* __restrict__ bias, const float* __restrict__ gam,
               const float* __restrict__ bet, float* __restrict__ out2)
{
  __shared__ float lA[64][33];
  __shared__ float lB[64][33];
  const int tid = threadIdx.x;
  const int m0 = blockIdx.y * 64;
  const int n0 = blockIdx.x * 64;
  const int tx = tid & 15;
  const int ty = tid >> 4;

  float acc[4][4];
  #pragma unroll
  for (int i=0;i<4;i++)
    #pragma unroll
    for (int j=0;j<4;j++) acc[i][j] = 0.f;

  const int nkt = (K + 31) >> 5;
  for (int kt = 0; kt < nkt; kt++){
    const int k0 = kt << 5;
    __syncthreads();
    #pragma unroll
    for (int c=0;c<8;c++){
      int lin = tid + c*256;
      int row = lin >> 5, col = lin & 31;
      int gm = m0 + row, gk = k0 + col;
      float va = 0.f, vb = 0.f;
      if (gm < M && gk < K)        va = A [(size_t)gm*lda + gk];
      if (n0+row < Ncol && gk < K) vb = Bt[(size_t)(n0+row)*ldb + gk];
      lA[row][col] = va;
      lB[row][col] = vb;
    }
    __syncthreads();
    #pragma unroll 4
    for (int kk=0; kk<32; kk++){
      float a0=lA[ty*4+0][kk], a1=lA[ty*4+1][kk], a2=lA[ty*4+2][kk], a3=lA[ty*4+3][kk];
      float b0=lB[tx*4+0][kk], b1=lB[tx*4+1][kk], b2=lB[tx*4+2][kk], b3=lB[tx*4+3][kk];
      acc[0][0]+=a0*b0; acc[0][1]+=a0*b1; acc[0][2]+=a0*b2; acc[0][3]+=a0*b3;
      acc[1][0]+=a1*b0; acc[1][1]+=a1*b1; acc[1][2]+=a1*b2; acc[1][3]+=a1*b3;
      acc[2][0]+=a2*b0; acc[2][1]+=a2*b1; acc[2][2]+=a2*b2; acc[2][3]+=a2*b3;
      acc[3][0]+=a3*b0; acc[3][1]+=a3*b1; acc[3][2]+=a3*b2; acc[3][3]+=a3*b3;
    }
  }
  const float BNS = 0.99995000374968755f;
  #pragma unroll
  for (int j=0;j<4;j++){
    int gn = n0 + tx*4 + j;
    if (gn >= Ncol) continue;
    float bi = bias[gn];
    float gs = gam[gn]*BNS, be = bet[gn];
    #pragma unroll
    for (int i=0;i<4;i++){
      int gm = m0 + ty*4 + i;
      if (gm >= M) continue;
      float v = acc[i][j] + bi;
      v = v*gs + be; v = v > 0.f ? v : expm1f(v);
      out1[(size_t)gm*ldc + gn] = v;
      out2[(size_t)gm*ldc + gn] = v;
    }
  }
}

// ---------------- CSR build --------------------------------------------------
__global__ void csr_cnt_k(const int* __restrict__ key, int* __restrict__ cnt){
  int e = blockIdx.x*256 + threadIdx.x;
  if (e < NE) atomicAdd(&cnt[key[e]], 1);
}
__global__ __launch_bounds__(256)
void csr_scan_k(const int* __restrict__ cnt, int* __restrict__ rowptr, int* __restrict__ cursor){
  __shared__ int part[256];
  int t = threadIdx.x;
  int base = t*24;
  int loc[24]; int s=0;
  #pragma unroll
  for (int u=0;u<24;u++){
    int idx = base+u;
    int v = (idx<NN) ? cnt[idx] : 0;
    loc[u] = s; s += v;
  }
  part[t] = s;
  __syncthreads();
  if (t==0){
    int run=0;
    for (int u=0;u<256;u++){ int tmp=part[u]; part[u]=run; run+=tmp; }
  }
  __syncthreads();
  int off = part[t];
  #pragma unroll
  for (int u=0;u<24;u++){
    int idx = base+u;
    if (idx<NN){ rowptr[idx]=off+loc[u]; cursor[idx]=off+loc[u]; }
  }
  if (t==255) rowptr[NN] = off + s;
}
__global__ void csr_fill_k(const int* __restrict__ key, int* __restrict__ cursor,
                           int* __restrict__ elist){
  int e = blockIdx.x*256 + threadIdx.x;
  if (e < NE){ int pos = atomicAdd(&cursor[key[e]], 1); elist[pos] = e; }
}

// ---------------- fused per-node attention (dst-CSR, no atomics) ------------
__global__ __launch_bounds__(256)
void attn_k(double* __restrict__ QKVS, const int* __restrict__ rowptr,
            const int* __restrict__ elist, const int* __restrict__ src,
            double* __restrict__ alpha)
{
  __shared__ double lg[4][128];
  const int w = threadIdx.x >> 6;
  const int node = blockIdx.x*4 + w;
  if (node >= NN) return;
  const int lane = threadIdx.x & 63;
  const int e0 = rowptr[node], e1 = rowptr[node+1];
  const int deg = e1 - e0;
  if (deg <= 0) return;
  const double SC = 0.088388347648318447; // 1/sqrt(128)
  const double* q = QKVS + (size_t)node*512;
  double q0 = q[lane], q1 = q[lane+64];

  if (deg <= 128){
    double m = -1.0e300;
    for (int i=0;i<deg;i++){
      const double* k = QKVS + (size_t)src[elist[e0+i]]*512 + 128;
      double p = q0*k[lane] + q1*k[lane+64];
      #pragma unroll
      for (int off=32; off; off>>=1) p += __shfl_xor(p, off);
      p *= SC;
      if (lane==0) lg[w][i] = p;
      m = fmax(m, p);
    }
    double S = 0.0;
    for (int i=0;i<deg;i++){
      double ex = exp(lg[w][i] - m);
      if (lane==0) lg[w][i] = ex;
      S += ex;
    }
    // NOTE: S computed from pre-overwrite read then lane0 overwrites; LDS ordering
    // within the wave is handled by lgkmcnt; reread after overwrite below.
    double inv = 1.0 / S;
    double o0 = QKVS[(size_t)node*512 + 384 + lane];
    double o1 = QKVS[(size_t)node*512 + 448 + lane];
    for (int i=0;i<deg;i++){
      int e = elist[e0+i];
      double a = lg[w][i] * inv;
      const double* v = QKVS + (size_t)src[e]*512 + 256;
      o0 = fma(a, v[lane],    o0);
      o1 = fma(a, v[lane+64], o1);
      if (lane==0) alpha[e] = a;
    }
    QKVS[(size_t)node*512 + 384 + lane] = o0;
    QKVS[(size_t)node*512 + 448 + lane] = o1;
  } else {
    // recompute fallback (deg > 128: essentially never)
    double m = -1.0e300;
    for (int i=0;i<deg;i++){
      const double* k = QKVS + (size_t)src[elist[e0+i]]*512 + 128;
      double p = q0*k[lane] + q1*k[lane+64];
      #pragma unroll
      for (int off=32; off; off>>=1) p += __shfl_xor(p, off);
      m = fmax(m, p*SC);
    }
    double S = 0.0;
    for (int i=0;i<deg;i++){
      const double* k = QKVS + (size_t)src[elist[e0+i]]*512 + 128;
      double p = q0*k[lane] + q1*k[lane+64];
      #pragma unroll
      for (int off=32; off; off>>=1) p += __shfl_xor(p, off);
      S += exp(p*SC - m);
    }
    double inv = 1.0 / S;
    double o0 = QKVS[(size_t)node*512 + 384 + lane];
    double o1 = QKVS[(size_t)node*512 + 448 + lane];
    for (int i=0;i<deg;i++){
      int e = elist[e0+i];
      const double* k = QKVS + (size_t)src[e]*512 + 128;
      double p = q0*k[lane] + q1*k[lane+64];
      #pragma unroll
      for (int off=32; off; off>>=1) p += __shfl_xor(p, off);
      double a = exp(p*SC - m) * inv;
      const double* v = QKVS + (size_t)src[e]*512 + 256;
      o0 = fma(a, v[lane],    o0);
      o1 = fma(a, v[lane+64], o1);
      if (lane==0) alpha[e] = a;
    }
    QKVS[(size_t)node*512 + 384 + lane] = o0;
    QKVS[(size_t)node*512 + 448 + lane] = o1;
  }
}

// ---------------- fused spmm over src-CSR (both graphs, no atomics) ---------
__global__ __launch_bounds__(256)
void spmm_csr_k(const double* __restrict__ QK1, const double* __restrict__ QK2,
                const int* __restrict__ rpSA, const int* __restrict__ elSA,
                const int* __restrict__ dstA, const double* __restrict__ aA,
                const int* __restrict__ rpSP, const int* __restrict__ elSP,
                const int* __restrict__ dstP, const double* __restrict__ aP,
                double* __restrict__ out, int ldo, int offo, int dorelu)
{
  const int node = blockIdx.x*4 + (threadIdx.x>>6);
  if (node >= NN) return;
  const int lane = threadIdx.x & 63;
  double a0 = 0.0, a1 = 0.0;
  for (int idx = rpSA[node]; idx < rpSA[node+1]; ++idx){
    int e = elSA[idx]; int d = dstA[e];
    if (d != node){
      double wgt = 0.5 * aA[e];
      const double* o = QK1 + (size_t)d*512 + 384;
      a0 = fma(wgt, o[lane],    a0);
      a1 = fma(wgt, o[lane+64], a1);
    }
  }
  for (int idx = rpSP[node]; idx < rpSP[node+1]; ++idx){
    int e = elSP[idx]; int d = dstP[e];
    if (d != node){
      double wgt = 0.5 * aP[e];
      const double* o = QK2 + (size_t)d*512 + 384;
      a0 = fma(wgt, o[lane],    a0);
      a1 = fma(wgt, o[lane+64], a1);
    }
  }
  if (dorelu){ a0 = fmax(a0, 0.0); a1 = fmax(a1, 0.0); }
  out[(size_t)node*ldo + offo + lane]      = a0;
  out[(size_t)node*ldo + offo + 64 + lane] = a1;
}

__global__ void att_scatter_k(const int* __restrict__ src, const int* __restrict__ dst,
                              const double* __restrict__ alpha, float* __restrict__ att)
{
  int e = blockIdx.x*256 + threadIdx.x;
  if (e >= NE) return;
  int s = src[e], d = dst[e];
  if (s == d) return;
  atomicAdd(&att[(size_t)s*NN + d], (float)alpha[e]);
}

// ---------------- f32 distance GEMM + fused per-tile top-12 -----------------
__global__ __launch_bounds__(256)
void dist32_k(const float* __restrict__ Z, const float* __restrict__ Znb,
              const float* __restrict__ sxA, const float* __restrict__ syA, const float* __restrict__ cjA,
              float* __restrict__ candV, int* __restrict__ candI)
{
  __shared__ __align__(16) char smem[34560];
  float (*lA)[33]    = (float(*)[33])(smem);
  float (*lB)[33]    = (float(*)[33])(smem + 8448);
  float (*stile)[129]= (float(*)[129])(smem);
  float* sSx = (float*)(smem + 33024);
  float* sSy = sSx + 128;
  float* sC  = sSy + 128;

  const int tid = threadIdx.x;
  const int m0 = blockIdx.y * 64;
  const int n0 = blockIdx.x * 128;
  const int tx = tid & 15;
  const int ty = tid >> 4;

  if (tid < 128){
    int jg = n0 + tid;
    if (jg < NN){ sSx[tid]=sxA[jg]; sSy[tid]=syA[jg]; sC[tid]=cjA[jg]; }
    else        { sSx[tid]=0.f; sSy[tid]=0.f; sC[tid]=-3e38f; }
  }

  float acc[4][8];
  #pragma unroll
  for (int i=0;i<4;i++)
    #pragma unroll
    for (int j=0;j<8;j++) acc[i][j] = 0.f;

  for (int kt = 0; kt < 8; kt++){
    const int k0 = kt << 5;
    __syncthreads();
    #pragma unroll
    for (int c=0;c<8;c++){
      int lin = tid + c*256;
      int row = lin >> 5, col = lin & 31;
      int gm = m0 + row;
      lA[row][col] = (gm < NN) ? Z[(size_t)gm*256 + k0 + col] : 0.f;
    }
    #pragma unroll
    for (int c=0;c<16;c++){
      int lin = tid + c*256;
      int row = lin >> 5, col = lin & 31;
      int gn = n0 + row;
      lB[row][col] = (gn < NN) ? Znb[(size_t)gn*256 + k0 + col] : 0.f;
    }
    __syncthreads();
    #pragma unroll 4
    for (int kk=0; kk<32; kk++){
      float a[4], b[8];
      #pragma unroll
      for (int i=0;i<4;i++) a[i] = lA[ty*4+i][kk];
      #pragma unroll
      for (int j=0;j<8;j++) b[j] = lB[tx*8+j][kk];
      #pragma unroll
      for (int i=0;i<4;i++)
        #pragma unroll
        for (int j=0;j<8;j++) acc[i][j] += a[i]*b[j];
    }
  }

  __syncthreads();
  #pragma unroll
  for (int i=0;i<4;i++)
    #pragma unroll
    for (int j=0;j<8;j++)
      stile[ty*4+i][tx*8+j] = acc[i][j];
  __syncthreads();

  if (tid < 64){
    const int gi = m0 + tid;
    if (gi < NN){
      float sxi = sxA[gi], syi = syA[gi];
      float tv[NCAND]; int ti[NCAND];
      #pragma unroll
      for (int p=0;p<NCAND;p++){ tv[p] = -3.4e38f; ti[p] = -1; }
      #pragma unroll 1
      for (int jj=0; jj<128; jj++){
        float s = 2.f*stile[tid][jj] + 2.f*(sxi*sSx[jj] + syi*sSy[jj]) + sC[jj];
        if (s > tv[NCAND-1]){
          bool g[NCAND];
          #pragma unroll
          for (int p=0;p<NCAND;p++) g[p] = s > tv[p];
          #pragma unroll
          for (int p=NCAND-1;p>0;--p) if (g[p-1]){ tv[p]=tv[p-1]; ti[p]=ti[p-1]; }
          #pragma unroll
          for (int p=0;p<NCAND;p++){ bool pl = g[p] && (p==0 || !g[p-1]); if (pl){ tv[p]=s; ti[p]=n0+jj; } }
        }
      }
      size_t base = ((size_t)gi*NTILE + blockIdx.x)*NCAND;
      #pragma unroll
      for (int p=0;p<NCAND;p++){ candV[base+p]=tv[p]; candI[base+p]=ti[p]; }
    }
  }
}

// ---------------- merge: f32 prefilter -> f64 wave rescore -> top-9 ---------
__global__ __launch_bounds__(256)
void merge64_k(const float* __restrict__ candV, const int* __restrict__ candI,
               const double* __restrict__ Z, const double* __restrict__ Znb,
               const double* __restrict__ sx64, const double* __restrict__ sy64,
               double* __restrict__ wgt9, int* __restrict__ idx9)
{
  __shared__ double zi[256];
  __shared__ float  fv[TCAND];
  __shared__ int    fj[TCAND];
  __shared__ float  tvs[PRE];
  __shared__ int    pj[PRE];
  __shared__ double ps[PRE];
  __shared__ double tv9[9];
  __shared__ int    ti9[9];

  const int i = blockIdx.x;
  const int t = threadIdx.x;
  zi[t] = Z[(size_t)i*256 + t];
  for (int c = t; c < TCAND; c += 256){
    fv[c] = candV[(size_t)i*TCAND + c];
    fj[c] = candI[(size_t)i*TCAND + c];
  }
  __syncthreads();

  if (t == 0){
    for (int p=0;p<PRE;p++){ tvs[p]=-3.4e38f; pj[p]=-1; }
    for (int c=0;c<TCAND;c++){
      float s = fv[c];
      if (!(s > tvs[PRE-1])) continue;
      int j = fj[c];
      if (j < 0) continue;
      int p = PRE-1;
      while (p > 0 && s > tvs[p-1]){ tvs[p]=tvs[p-1]; pj[p]=pj[p-1]; --p; }
      tvs[p]=s; pj[p]=j;
    }
  }
  __syncthreads();

  const int wv = t >> 6, lane = t & 63;
  const double sxi = sx64[i], syi = sy64[i];
  for (int c = wv; c < PRE; c += 4){
    int j = pj[c];
    double s = -1.0e300;
    if (j >= 0){
      const double* zj = Znb + (size_t)j*256;
      double p = 0.0;
      #pragma unroll
      for (int u=0;u<4;u++){
        double b = zj[lane + 64*u];
        double a = zi[lane + 64*u];
        p = fma(2.0*a - b, b, p);     // += 2ab - b^2
      }
      #pragma unroll
      for (int off=32; off; off>>=1) p += __shfl_xor(p, off);
      double sxj = sx64[j], syj = sy64[j];
      s = p + 2.0*(sxi*sxj + syi*syj) - (sxj*sxj + syj*syj);
    }
    if (lane == 0) ps[c] = s;
  }
  __syncthreads();

  if (t == 0){
    for (int p=0;p<9;p++){ tv9[p]=-1.0e301; ti9[p]=0x7FFFFFFF; }
    for (int c=0;c<PRE;c++){
      double s = ps[c]; int j = pj[c];
      if (j < 0 || s < -1.0e299) continue;
      if (!((s > tv9[8]) || (s == tv9[8] && j < ti9[8]))) continue;
      int p = 8;
      while (p > 0 && ((s > tv9[p-1]) || (s == tv9[p-1] && j < ti9[p-1]))){
        tv9[p]=tv9[p-1]; ti9[p]=ti9[p-1]; --p;
      }
      tv9[p]=s; ti9[p]=j;
    }
    double m = tv9[0], e[9], S=0.0;
    for (int k=0;k<9;k++){ e[k]=exp(tv9[k]-m); S+=e[k]; }
    for (int k=0;k<9;k++){
      wgt9[(size_t)i*9+k] = e[k]/S;
      idx9[(size_t)i*9+k] = ti9[k];
    }
  }
}

// ---------------- znb prep + casts ------------------------------------------
__global__ __launch_bounds__(256)
void znbprep_k(const double* __restrict__ znb, const double* __restrict__ ssq64,
               float* __restrict__ cjA)
{
  __shared__ double red[256];
  int i = blockIdx.x, d = threadIdx.x;
  double v = znb[(size_t)i*256 + d];
  red[d] = v*v;
  __syncthreads();
  for (int s=128; s; s>>=1){ if (d<s) red[d]+=red[d+s]; __syncthreads(); }
  if (d==0) cjA[i] = -(float)(red[0] + ssq64[i]);
}
__global__ void castz_k(const double* __restrict__ z64, float* __restrict__ z32, int n){
  int t = blockIdx.x*256+threadIdx.x;
  if (t < n) z32[t] = (float)z64[t];
}
__global__ void featout_k(const double* __restrict__ z, float* __restrict__ o){
  int t = blockIdx.x*256+threadIdx.x;
  if (t < NN*128){ int i=t>>7, d=t&127; o[t] = (float)z[(size_t)i*256 + d]; }
}

__global__ __launch_bounds__(256)
void zout_k(const double* __restrict__ Z, const double* __restrict__ Znb,
            const int* __restrict__ idx9, const double* __restrict__ wgt9,
            float* __restrict__ zoOut, float* __restrict__ zoF32, float* __restrict__ x1)
{
  int i = blockIdx.x; int d = threadIdx.x;
  double a = Z[(size_t)i*256 + d];
  #pragma unroll
  for (int k=0;k<9;k++){
    int j = idx9[(size_t)i*9+k];
    double w = wgt9[(size_t)i*9+k];
    double t = w * Znb[(size_t)j*256 + d];
    a += t;
    x1[((size_t)i*9+k)*256 + d] = (float)t;
  }
  float af = (float)a;
  zoOut[(size_t)i*256+d] = af;
  zoF32[(size_t)i*256+d] = af;
}

__global__ __launch_bounds__(256)
void q_k(const float* __restrict__ zoF, const float* __restrict__ clus, float* __restrict__ qB)
{
  __shared__ float wred[10][4];
  __shared__ float qs[10];
  int i = blockIdx.x, d = threadIdx.x;
  int lane = d & 63, wv = d >> 6;
  float zo = zoF[(size_t)i*256 + d];
  #pragma unroll
  for (int c=0;c<10;c++){
    float df = zo - clus[(size_t)c*256 + d];
    float p = df*df;
    #pragma unroll
    for (int off=32; off; off>>=1) p += __shfl_down(p, off);
    if (lane == 0) wred[c][wv] = p;
  }
  __syncthreads();
  if (d < 10){
    float d2 = wred[d][0]+wred[d][1]+wred[d][2]+wred[d][3];
    qs[d] = 1.f/(1.f + d2);
  }
  __syncthreads();
  if (d < 10){
    float s = 0.f;
    #pragma unroll
    for (int c=0;c<10;c++) s += qs[c];
    qB[(size_t)i*10 + d] = qs[d]/s;
  }
}

// ---------------- host ------------------------------------------------------
extern "C" void kernel_launch(void* const* d_in, const int* in_sizes, int n_in,
                              void* d_out, int out_size, void* d_ws, size_t ws_size,
                              hipStream_t stream)
{
  (void)in_sizes; (void)n_in; (void)out_size; (void)ws_size;
  const float* x    = (const float*)d_in[0];
  const float* xnb  = (const float*)d_in[1];
  const float* spat = (const float*)d_in[2];
  const int*   adj  = (const int*)d_in[3];
  const int*   adjp = (const int*)d_in[4];
  const float* W1   = (const float*)d_in[5];
  const float* b1   = (const float*)d_in[6];
  const float* g1   = (const float*)d_in[7];
  const float* be1  = (const float*)d_in[8];
  const float* W2   = (const float*)d_in[9];
  const float* b2   = (const float*)d_in[10];
  const float* g2   = (const float*)d_in[11];
  const float* be2  = (const float*)d_in[12];
  const float* Wq   = (const float*)d_in[13];
  const float* Wk   = (const float*)d_in[14];
  const float* Wv   = (const float*)d_in[15];
  const float* Wsm  = (const float*)d_in[16];
  const float* bq   = (const float*)d_in[17];
  const float* bk   = (const float*)d_in[18];
  const float* bv   = (const float*)d_in[19];
  const float* bs   = (const float*)d_in[20];
  const float* decW = (const float*)d_in[21];
  const float* decb = (const float*)d_in[22];
  const float* decg = (const float*)d_in[23];
  const float* decbe= (const float*)d_in[24];
  const float* clus = (const float*)d_in[25];
  float* outF = (float*)d_out;
  const int* srcA = adj,  *dstA = adj + NE;
  const int* srcP = adjp, *dstP = adjp + NE;

  char* wsb = (char*)d_ws;
  size_t off = 0;
  auto alloc = [&](size_t bytes)->char*{
    char* p = wsb + off;
    off = (off + bytes + 255) & ~(size_t)255;
    return p;
  };
  double* W1t  = (double*)alloc(768000*8);
  double* W2t  = (double*)alloc(32768*8);
  double* Bct  = (double*)alloc(196608*8);
  float*  Dt   = (float*) alloc(768000*4);
  double* bcat = (double*)alloc(1536*8);
  double* sx64 = (double*)alloc(NN*8);
  double* sy64 = (double*)alloc(NN*8);
  double* ssq64= (double*)alloc(NN*8);
  float*  sx32 = (float*) alloc(NN*4);
  float*  sy32 = (float*) alloc(NN*4);
  double* b1c  = (double*)alloc(256*8);
  double* b2c  = (double*)alloc(128*8);
  double* H1   = (double*)alloc((size_t)NN*256*8);
  double* zX64 = (double*)alloc((size_t)NN*256*8);
  double* zNB64= (double*)alloc((size_t)NN*256*8);
  double* hcur = (double*)alloc((size_t)NN*128*8);
  double* QK1  = (double*)alloc((size_t)NN*512*8);
  double* QK2  = (double*)alloc((size_t)NN*512*8);
  double* alphaA=(double*)alloc((size_t)NE*8);
  double* alphaP=(double*)alloc((size_t)NE*8);
  // CSRs
  int* rpDA = (int*)alloc((NN+1)*4);
  int* rpDP = (int*)alloc((NN+1)*4);
  int* rpSA = (int*)alloc((NN+1)*4);
  int* rpSP = (int*)alloc((NN+1)*4);
  int* curDA= (int*)alloc(NN*4);
  int* curDP= (int*)alloc(NN*4);
  int* curSA= (int*)alloc(NN*4);
  int* curSP= (int*)alloc(NN*4);
  int* elDA = (int*)alloc(NE*4);
  int* elDP = (int*)alloc(NE*4);
  int* elSA = (int*)alloc(NE*4);
  int* elSP = (int*)alloc(NE*4);
  float*  zX32 = (float*) alloc((size_t)NN*256*4);
  float*  zNB32= (float*) alloc((size_t)NN*256*4);
  float*  cjA  = (float*) alloc(NN*4);
  float*  candV= (float*) alloc((size_t)NN*TCAND*4);
  int*    candI= (int*)   alloc((size_t)NN*TCAND*4);
  int*    idx9 = (int*)   alloc((size_t)NN*9*4);
  double* wgt9 = (double*)alloc((size_t)NN*9*8);
  float*  zoF32= (float*) alloc((size_t)NN*256*4);

  prep_k<<<6926, 256, 0, stream>>>(W1, W2, Wq, Wk, Wv, Wsm, bq, bk, bv, bs, decW, spat,
                                   W1t, W2t, Bct, Dt, bcat,
                                   sx64, sy64, ssq64, sx32, sy32);
  castup_k<<<1, 256, 0, stream>>>(b1, b1c, 256);
  castup_k<<<1, 256, 0, stream>>>(b2, b2c, 128);

  // CSR build (4 CSRs)
  hipMemsetAsync(curDA, 0, NN*4, stream);
  hipMemsetAsync(curDP, 0, NN*4, stream);
  hipMemsetAsync(curSA, 0, NN*4, stream);
  hipMemsetAsync(curSP, 0, NN*4, stream);
  csr_cnt_k<<<375, 256, 0, stream>>>(dstA, curDA);
  csr_cnt_k<<<375, 256, 0, stream>>>(dstP, curDP);
  csr_cnt_k<<<375, 256, 0, stream>>>(srcA, curSA);
  csr_cnt_k<<<375, 256, 0, stream>>>(srcP, curSP);
  csr_scan_k<<<1, 256, 0, stream>>>(curDA, rpDA, curDA);
  csr_scan_k<<<1, 256, 0, stream>>>(curDP, rpDP, curDP);
  csr_scan_k<<<1, 256, 0, stream>>>(curSA, rpSA, curSA);
  csr_scan_k<<<1, 256, 0, stream>>>(curSP, rpSP, curSP);
  csr_fill_k<<<375, 256, 0, stream>>>(dstA, curDA, elDA);
  csr_fill_k<<<375, 256, 0, stream>>>(dstP, curDP, elDP);
  csr_fill_k<<<375, 256, 0, stream>>>(srcA, curSA, elSA);
  csr_fill_k<<<375, 256, 0, stream>>>(srcP, curSP, elSP);

  auto enc = [&](const float* xin, double* zbuf, bool isX){
    gemm64_k<1,float><<<dim3(4,94), 256, 0, stream>>>(xin, KDIN, W1t, KDIN, NN, KDIN, 256,
                                                      H1, 256, b1c, g1, be1, nullptr);
    gemm64_k<1,double><<<dim3(2,94), 256, 0, stream>>>(H1, 256, W2t, 256, NN, 256, 128,
                                                       zbuf, 256, b2c, g2, be2, nullptr);
    const double* hin = zbuf; int ldh = 256;
    for (int l=0; l<3; l++){
      const double* Bh = Bct + (size_t)l*65536;
      const double* bc = bcat + l*512;
      if (l != 1){
        gemm64_k<0,double><<<dim3(8,94), 256, 0, stream>>>(hin, ldh, Bh, 128, NN, 128, 512,
                                                           QK1, 512, bc, nullptr, nullptr, QK2);
        attn_k<<<1500, 256, 0, stream>>>(QK1, rpDA, elDA, srcA, alphaA);
        attn_k<<<1500, 256, 0, stream>>>(QK2, rpDP, elDP, srcP, alphaP);
      } else {
        gemm64_k<0,double><<<dim3(8,94), 256, 0, stream>>>(hin, ldh, Bh, 128, NN, 128, 512,
                                                           QK1, 512, bc, nullptr, nullptr, nullptr);
        attn_k<<<1500, 256, 0, stream>>>(QK1, rpDA, elDA, srcA, alphaA);
        gemm64_k<0,double><<<dim3(8,94), 256, 0, stream>>>(QK1 + 384, 512, Bh, 128, NN, 128, 512,
                                                           QK2, 512, bc, nullptr, nullptr, nullptr);
        attn_k<<<1500, 256, 0, stream>>>(QK2, rpDP, elDP, srcP, alphaP);
      }
      if (isX && l == 2){
        hipMemsetAsync(outF + (size_t)OFF_ATT, 0, (size_t)NN*NN*4, stream);
        att_scatter_k<<<375, 256, 0, stream>>>(srcP, dstP, alphaP, outF + (size_t)OFF_ATT);
      }
      if (l < 2){
        spmm_csr_k<<<1500, 256, 0, stream>>>(QK1, QK2, rpSA, elSA, dstA, alphaA,
                                             rpSP, elSP, dstP, alphaP, hcur, 128, 0, 1);
        hin = hcur; ldh = 128;
      } else {
        spmm_csr_k<<<1500, 256, 0, stream>>>(QK1, QK2, rpSA, elSA, dstA, alphaA,
                                             rpSP, elSP, dstP, alphaP, zbuf, 256, 128, 0);
      }
    }
  };
  enc(x,   zX64,  true);
  enc(xnb, zNB64, false);

  castz_k<<<6000, 256, 0, stream>>>(zX64,  zX32,  NN*256);
  castz_k<<<6000, 256, 0, stream>>>(zNB64, zNB32, NN*256);
  znbprep_k<<<NN, 256, 0, stream>>>(zNB64, ssq64, cjA);
  dist32_k<<<dim3(NTILE,94), 256, 0, stream>>>(zX32, zNB32, sx32, sy32, cjA, candV, candI);
  merge64_k<<<NN, 256, 0, stream>>>(candV, candI, zX64, zNB64, sx64, sy64, wgt9, idx9);

  zout_k<<<NN, 256, 0, stream>>>(zX64, zNB64, idx9, wgt9,
                                 outF + (size_t)OFF_ZOUT, zoF32, outF + (size_t)OFF_X1);
  gemm32d_k<<<dim3(47,94), 256, 0, stream>>>(zoF32, 256, Dt, 256, NN, 256, 3000,
                                             outF + (size_t)OFF_DE1, 3000, decb, decg, decbe,
                                             outF + (size_t)OFF_DE2);
  q_k<<<NN, 256, 0, stream>>>(zoF32, clus, outF + (size_t)OFF_Q);
  featout_k<<<3000, 256, 0, stream>>>(zX64, outF + (size_t)OFF_FEAT);
}

// Round 10
// 3857.898 us; speedup vs baseline: 1.8583x; 1.3517x over previous
//
#include <hip/hip_runtime.h>
#include <hip/hip_bf16.h>
#include <math.h>
#include <stdint.h>

#define NN 6000
#define NE 96000
#define KDIN 3000
#define NCAND 12            // candidates per 128-col tile
#define NTILE 47
#define TCAND (NCAND*NTILE) // 564 per row
#define PRE 32              // f64-rescored candidates per row

// output element offsets (d_out is FLOAT32)
#define OFF_ZOUT 0
#define OFF_DE1  1536000
#define OFF_Q    19536000
#define OFF_FEAT 19596000
#define OFF_DE2  20364000
#define OFF_X1   38364000
#define OFF_ATT  52188000

// ---------------- weight prep: transpose, cast to f64 -----------------------
__global__ void prep_k(const float* __restrict__ W1, const float* __restrict__ W2,
                       const float* __restrict__ Wq, const float* __restrict__ Wk,
                       const float* __restrict__ Wv, const float* __restrict__ Ws,
                       const float* __restrict__ bq, const float* __restrict__ bk,
                       const float* __restrict__ bv, const float* __restrict__ bs,
                       const float* __restrict__ decW, const float* __restrict__ spat,
                       double* __restrict__ W1t, double* __restrict__ W2t,
                       double* __restrict__ Bct, float* __restrict__ Dt,
                       double* __restrict__ bcat,
                       double* __restrict__ sx64, double* __restrict__ sy64,
                       double* __restrict__ ssq64,
                       float* __restrict__ sx32, float* __restrict__ sy32)
{
  int t = blockIdx.x * 256 + threadIdx.x;
  if (t < 768000){
    int n = t / 3000, k = t % 3000;
    W1t[t] = (double)W1[(size_t)k * 256 + n]; return;
  }
  t -= 768000;
  if (t < 32768){
    int n = t / 256, k = t % 256;
    W2t[t] = (double)W2[(size_t)k * 128 + n]; return;
  }
  t -= 32768;
  if (t < 196608){
    int l = t / 65536; int rem = t % 65536;
    int n = rem / 128, k = rem % 128;
    int sel = n >> 7, nn = n & 127;
    const float* Wm = sel==0 ? Wq : sel==1 ? Wk : sel==2 ? Wv : Ws;
    Bct[t] = (double)Wm[((size_t)(l*128) + k) * 128 + nn]; return;
  }
  t -= 196608;
  if (t < 768000){
    int n = t / 256, k = t % 256;
    Dt[t] = decW[(size_t)k * 3000 + n]; return;
  }
  t -= 768000;
  if (t < 1536){
    int l = t / 512, n = t % 512;
    int sel = n >> 7, nn = n & 127;
    const float* bm = sel==0 ? bq : sel==1 ? bk : sel==2 ? bv : bs;
    bcat[t] = (double)bm[l*128 + nn]; return;
  }
  t -= 1536;
  if (t < NN){
    float sx = spat[(size_t)t*2], sy = spat[(size_t)t*2+1];
    sx64[t]=(double)sx; sy64[t]=(double)sy;
    ssq64[t]=(double)sx*(double)sx + (double)sy*(double)sy;
    sx32[t]=sx; sy32[t]=sy; return;
  }
}

__global__ void castup_k(const float* __restrict__ s, double* __restrict__ d, int n){
  int t = blockIdx.x*256 + threadIdx.x;
  if (t < n) d[t] = (double)s[t];
}

// ---------------- f64 vector GEMM, NT, 64x64, conflict-free frags -----------
// fragment map: row = ty + 16*i, col = tx + 16*j  (bank-conflict-free for f64)
// EPI 0: out = acc + bias (optional dual write)
template<int EPI, typename TA>
__global__ __launch_bounds__(256)
void gemm64_k(const TA* __restrict__ A, int lda,
              const double* __restrict__ Bt, int ldb,
              int M, int K, int Ncol,
              double* __restrict__ outF, int ldc,
              const double* __restrict__ bias,
              const float* __restrict__ gam, const float* __restrict__ bet,
              double* __restrict__ outF2)
{
  __shared__ double lA[64][33];
  __shared__ double lB[64][33];
  const int tid = threadIdx.x;
  const int m0 = blockIdx.y * 64;
  const int n0 = blockIdx.x * 64;
  const int tx = tid & 15;
  const int ty = tid >> 4;

  double acc[4][4];
  #pragma unroll
  for (int i=0;i<4;i++)
    #pragma unroll
    for (int j=0;j<4;j++) acc[i][j] = 0.0;

  const int nkt = (K + 31) >> 5;
  for (int kt = 0; kt < nkt; kt++){
    const int k0 = kt << 5;
    __syncthreads();
    #pragma unroll
    for (int c=0;c<8;c++){
      int lin = tid + c*256;
      int row = lin >> 5, col = lin & 31;
      int gm = m0 + row, gk = k0 + col;
      double va = 0.0, vb = 0.0;
      if (gm < M && gk < K)        va = (double)A [(size_t)gm*lda + gk];
      if (n0+row < Ncol && gk < K) vb = Bt[(size_t)(n0+row)*ldb + gk];
      lA[row][col] = va;
      lB[row][col] = vb;
    }
    __syncthreads();
    #pragma unroll 2
    for (int kk=0; kk<32; kk++){
      double a0=lA[ty][kk], a1=lA[ty+16][kk], a2=lA[ty+32][kk], a3=lA[ty+48][kk];
      double b0=lB[tx][kk], b1=lB[tx+16][kk], b2=lB[tx+32][kk], b3=lB[tx+48][kk];
      acc[0][0]+=a0*b0; acc[0][1]+=a0*b1; acc[0][2]+=a0*b2; acc[0][3]+=a0*b3;
      acc[1][0]+=a1*b0; acc[1][1]+=a1*b1; acc[1][2]+=a1*b2; acc[1][3]+=a1*b3;
      acc[2][0]+=a2*b0; acc[2][1]+=a2*b1; acc[2][2]+=a2*b2; acc[2][3]+=a2*b3;
      acc[3][0]+=a3*b0; acc[3][1]+=a3*b1; acc[3][2]+=a3*b2; acc[3][3]+=a3*b3;
    }
  }
  #pragma unroll
  for (int j=0;j<4;j++){
    int gn = n0 + tx + 16*j;
    if (gn >= Ncol) continue;
    double bi = bias[gn];
    #pragma unroll
    for (int i=0;i<4;i++){
      int gm = m0 + ty + 16*i;
      if (gm >= M) continue;
      double v = acc[i][j] + bi;
      outF[(size_t)gm*ldc + gn] = v;
      if (outF2) outF2[(size_t)gm*ldc + gn] = v;
    }
  }
}

// ---------------- split-K f64 GEMM: partial per blockIdx.z ------------------
template<typename TA>
__global__ __launch_bounds__(256)
void gemm64s_k(const TA* __restrict__ A, int lda,
               const double* __restrict__ Bt, int ldb,
               int M, int K, int kchunk, int Ncol,
               double* __restrict__ part)   // [z][M*Ncol]
{
  __shared__ double lA[64][33];
  __shared__ double lB[64][33];
  const int tid = threadIdx.x;
  const int m0 = blockIdx.y * 64;
  const int n0 = blockIdx.x * 64;
  const int tx = tid & 15;
  const int ty = tid >> 4;
  const int kbeg = blockIdx.z * kchunk;
  const int kend = min(K, kbeg + kchunk);
  double* dst = part + (size_t)blockIdx.z * M * Ncol;

  double acc[4][4];
  #pragma unroll
  for (int i=0;i<4;i++)
    #pragma unroll
    for (int j=0;j<4;j++) acc[i][j] = 0.0;

  const int nkt = (kend - kbeg + 31) >> 5;
  for (int kt = 0; kt < nkt; kt++){
    const int k0 = kbeg + (kt << 5);
    __syncthreads();
    #pragma unroll
    for (int c=0;c<8;c++){
      int lin = tid + c*256;
      int row = lin >> 5, col = lin & 31;
      int gm = m0 + row, gk = k0 + col;
      double va = 0.0, vb = 0.0;
      if (gm < M && gk < kend)        va = (double)A [(size_t)gm*lda + gk];
      if (n0+row < Ncol && gk < kend) vb = Bt[(size_t)(n0+row)*ldb + gk];
      lA[row][col] = va;
      lB[row][col] = vb;
    }
    __syncthreads();
    #pragma unroll 2
    for (int kk=0; kk<32; kk++){
      double a0=lA[ty][kk], a1=lA[ty+16][kk], a2=lA[ty+32][kk], a3=lA[ty+48][kk];
      double b0=lB[tx][kk], b1=lB[tx+16][kk], b2=lB[tx+32][kk], b3=lB[tx+48][kk];
      acc[0][0]+=a0*b0; acc[0][1]+=a0*b1; acc[0][2]+=a0*b2; acc[0][3]+=a0*b3;
      acc[1][0]+=a1*b0; acc[1][1]+=a1*b1; acc[1][2]+=a1*b2; acc[1][3]+=a1*b3;
      acc[2][0]+=a2*b0; acc[2][1]+=a2*b1; acc[2][2]+=a2*b2; acc[2][3]+=a2*b3;
      acc[3][0]+=a3*b0; acc[3][1]+=a3*b1; acc[3][2]+=a3*b2; acc[3][3]+=a3*b3;
    }
  }
  #pragma unroll
  for (int j=0;j<4;j++){
    int gn = n0 + tx + 16*j;
    if (gn >= Ncol) continue;
    #pragma unroll
    for (int i=0;i<4;i++){
      int gm = m0 + ty + 16*i;
      if (gm >= M) continue;
      dst[(size_t)gm*Ncol + gn] = acc[i][j];
    }
  }
}

// reduce partials + bias + BN + ELU -> out (f64)
__global__ void epi64_k(const double* __restrict__ part, int nsplit, size_t pstride,
                        int M, int Ncol, const double* __restrict__ bias,
                        const float* __restrict__ gam, const float* __restrict__ bet,
                        double* __restrict__ out, int ldo)
{
  int t = blockIdx.x*256 + threadIdx.x;
  if (t >= M*Ncol) return;
  int gm = t / Ncol, gn = t - gm*Ncol;
  double v = 0.0;
  for (int s=0; s<nsplit; s++) v += part[(size_t)s*pstride + t];
  const double BNS = 0.99995000374968755261;
  v += bias[gn];
  v = v * ((double)gam[gn]*BNS) + (double)bet[gn];
  v = v > 0.0 ? v : expm1(v);
  out[(size_t)gm*ldo + gn] = v;
}

// ---------------- f32 GEMM (decoder, elu-bn to two f32 outs) ----------------
__global__ __launch_bounds__(256)
void gemm32d_k(const float* __restrict__ A, int lda,
               const float* __restrict__ Bt, int ldb,
               int M, int K, int Ncol,
               float* __restrict__ out1, int ldc,
               const float* __restrict__ bias, const float* __restrict__ gam,
               const float* __restrict__ bet, float* __restrict__ out2)
{
  __shared__ float lA[64][33];
  __shared__ float lB[64][33];
  const int tid = threadIdx.x;
  const int m0 = blockIdx.y * 64;
  const int n0 = blockIdx.x * 64;
  const int tx = tid & 15;
  const int ty = tid >> 4;

  float acc[4][4];
  #pragma unroll
  for (int i=0;i<4;i++)
    #pragma unroll
    for (int j=0;j<4;j++) acc[i][j] = 0.f;

  const int nkt = (K + 31) >> 5;
  for (int kt = 0; kt < nkt; kt++){
    const int k0 = kt << 5;
    __syncthreads();
    #pragma unroll
    for (int c=0;c<8;c++){
      int lin = tid + c*256;
      int row = lin >> 5, col = lin & 31;
      int gm = m0 + row, gk = k0 + col;
      float va = 0.f, vb = 0.f;
      if (gm < M && gk < K)        va = A [(size_t)gm*lda + gk];
      if (n0+row < Ncol && gk < K) vb = Bt[(size_t)(n0+row)*ldb + gk];
      lA[row][col] = va;
      lB[row][col] = vb;
    }
    __syncthreads();
    #pragma unroll 4
    for (int kk=0; kk<32; kk++){
      float a0=lA[ty][kk], a1=lA[ty+16][kk], a2=lA[ty+32][kk], a3=lA[ty+48][kk];
      float b0=lB[tx][kk], b1=lB[tx+16][kk], b2=lB[tx+32][kk], b3=lB[tx+48][kk];
      acc[0][0]+=a0*b0; acc[0][1]+=a0*b1; acc[0][2]+=a0*b2; acc[0][3]+=a0*b3;
      acc[1][0]+=a1*b0; acc[1][1]+=a1*b1; acc[1][2]+=a1*b2; acc[1][3]+=a1*b3;
      acc[2][0]+=a2*b0; acc[2][1]+=a2*b1; acc[2][2]+=a2*b2; acc[2][3]+=a2*b3;
      acc[3][0]+=a3*b0; acc[3][1]+=a3*b1; acc[3][2]+=a3*b2; acc[3][3]+=a3*b3;
    }
  }
  const float BNS = 0.99995000374968755f;
  #pragma unroll
  for (int j=0;j<4;j++){
    int gn = n0 + tx + 16*j;
    if (gn >= Ncol) continue;
    float bi = bias[gn];
    float gs = gam[gn]*BNS, be = bet[gn];
    #pragma unroll
    for (int i=0;i<4;i++){
      int gm = m0 + ty + 16*i;
      if (gm >= M) continue;
      float v = acc[i][j] + bi;
      v = v*gs + be; v = v > 0.f ? v : expm1f(v);
      out1[(size_t)gm*ldc + gn] = v;
      out2[(size_t)gm*ldc + gn] = v;
    }
  }
}

// ---------------- CSR build --------------------------------------------------
__global__ void csr_cnt_k(const int* __restrict__ key, int* __restrict__ cnt){
  int e = blockIdx.x*256 + threadIdx.x;
  if (e < NE) atomicAdd(&cnt[key[e]], 1);
}
__global__ __launch_bounds__(256)
void csr_scan_k(const int* __restrict__ cnt, int* __restrict__ rowptr, int* __restrict__ cursor){
  __shared__ int part[256];
  int t = threadIdx.x;
  int base = t*24;
  int loc[24]; int s=0;
  #pragma unroll
  for (int u=0;u<24;u++){
    int idx = base+u;
    int v = (idx<NN) ? cnt[idx] : 0;
    loc[u] = s; s += v;
  }
  part[t] = s;
  __syncthreads();
  if (t==0){
    int run=0;
    for (int u=0;u<256;u++){ int tmp=part[u]; part[u]=run; run+=tmp; }
  }
  __syncthreads();
  int off = part[t];
  #pragma unroll
  for (int u=0;u<24;u++){
    int idx = base+u;
    if (idx<NN){ rowptr[idx]=off+loc[u]; cursor[idx]=off+loc[u]; }
  }
  if (t==255) rowptr[NN] = off + s;
}
__global__ void csr_fill_k(const int* __restrict__ key, int* __restrict__ cursor,
                           int* __restrict__ elist){
  int e = blockIdx.x*256 + threadIdx.x;
  if (e < NE){ int pos = atomicAdd(&cursor[key[e]], 1); elist[pos] = e; }
}

// ---------------- fused per-node attention (dst-CSR, no atomics) ------------
__global__ __launch_bounds__(256)
void attn_k(double* __restrict__ QKVS, const int* __restrict__ rowptr,
            const int* __restrict__ elist, const int* __restrict__ src,
            double* __restrict__ alpha)
{
  __shared__ double lg[4][128];
  const int w = threadIdx.x >> 6;
  const int node = blockIdx.x*4 + w;
  if (node >= NN) return;
  const int lane = threadIdx.x & 63;
  const int e0 = rowptr[node], e1 = rowptr[node+1];
  const int deg = e1 - e0;
  if (deg <= 0) return;
  const double SC = 0.088388347648318447; // 1/sqrt(128)
  const double* q = QKVS + (size_t)node*512;
  double q0 = q[lane], q1 = q[lane+64];

  if (deg <= 128){
    double m = -1.0e300;
    for (int i=0;i<deg;i++){
      const double* k = QKVS + (size_t)src[elist[e0+i]]*512 + 128;
      double p = q0*k[lane] + q1*k[lane+64];
      #pragma unroll
      for (int off=32; off; off>>=1) p += __shfl_xor(p, off);
      p *= SC;
      if (lane==0) lg[w][i] = p;
      m = fmax(m, p);
    }
    double S = 0.0;
    for (int i=0;i<deg;i++){
      double ex = exp(lg[w][i] - m);
      if (lane==0) lg[w][i] = ex;
      S += ex;
    }
    double inv = 1.0 / S;
    double o0 = QKVS[(size_t)node*512 + 384 + lane];
    double o1 = QKVS[(size_t)node*512 + 448 + lane];
    for (int i=0;i<deg;i++){
      int e = elist[e0+i];
      double a = lg[w][i] * inv;
      const double* v = QKVS + (size_t)src[e]*512 + 256;
      o0 = fma(a, v[lane],    o0);
      o1 = fma(a, v[lane+64], o1);
      if (lane==0) alpha[e] = a;
    }
    QKVS[(size_t)node*512 + 384 + lane] = o0;
    QKVS[(size_t)node*512 + 448 + lane] = o1;
  } else {
    double m = -1.0e300;
    for (int i=0;i<deg;i++){
      const double* k = QKVS + (size_t)src[elist[e0+i]]*512 + 128;
      double p = q0*k[lane] + q1*k[lane+64];
      #pragma unroll
      for (int off=32; off; off>>=1) p += __shfl_xor(p, off);
      m = fmax(m, p*SC);
    }
    double S = 0.0;
    for (int i=0;i<deg;i++){
      const double* k = QKVS + (size_t)src[elist[e0+i]]*512 + 128;
      double p = q0*k[lane] + q1*k[lane+64];
      #pragma unroll
      for (int off=32; off; off>>=1) p += __shfl_xor(p, off);
      S += exp(p*SC - m);
    }
    double inv = 1.0 / S;
    double o0 = QKVS[(size_t)node*512 + 384 + lane];
    double o1 = QKVS[(size_t)node*512 + 448 + lane];
    for (int i=0;i<deg;i++){
      int e = elist[e0+i];
      const double* k = QKVS + (size_t)src[e]*512 + 128;
      double p = q0*k[lane] + q1*k[lane+64];
      #pragma unroll
      for (int off=32; off; off>>=1) p += __shfl_xor(p, off);
      double a = exp(p*SC - m) * inv;
      const double* v = QKVS + (size_t)src[e]*512 + 256;
      o0 = fma(a, v[lane],    o0);
      o1 = fma(a, v[lane+64], o1);
      if (lane==0) alpha[e] = a;
    }
    QKVS[(size_t)node*512 + 384 + lane] = o0;
    QKVS[(size_t)node*512 + 448 + lane] = o1;
  }
}

// ---------------- fused spmm over src-CSR (both graphs, no atomics) ---------
__global__ __launch_bounds__(256)
void spmm_csr_k(const double* __restrict__ QK1, const double* __restrict__ QK2,
                const int* __restrict__ rpSA, const int* __restrict__ elSA,
                const int* __restrict__ dstA, const double* __restrict__ aA,
                const int* __restrict__ rpSP, const int* __restrict__ elSP,
                const int* __restrict__ dstP, const double* __restrict__ aP,
                double* __restrict__ out, int ldo, int offo, int dorelu)
{
  const int node = blockIdx.x*4 + (threadIdx.x>>6);
  if (node >= NN) return;
  const int lane = threadIdx.x & 63;
  double a0 = 0.0, a1 = 0.0;
  for (int idx = rpSA[node]; idx < rpSA[node+1]; ++idx){
    int e = elSA[idx]; int d = dstA[e];
    if (d != node){
      double wgt = 0.5 * aA[e];
      const double* o = QK1 + (size_t)d*512 + 384;
      a0 = fma(wgt, o[lane],    a0);
      a1 = fma(wgt, o[lane+64], a1);
    }
  }
  for (int idx = rpSP[node]; idx < rpSP[node+1]; ++idx){
    int e = elSP[idx]; int d = dstP[e];
    if (d != node){
      double wgt = 0.5 * aP[e];
      const double* o = QK2 + (size_t)d*512 + 384;
      a0 = fma(wgt, o[lane],    a0);
      a1 = fma(wgt, o[lane+64], a1);
    }
  }
  if (dorelu){ a0 = fmax(a0, 0.0); a1 = fmax(a1, 0.0); }
  out[(size_t)node*ldo + offo + lane]      = a0;
  out[(size_t)node*ldo + offo + 64 + lane] = a1;
}

__global__ void att_scatter_k(const int* __restrict__ src, const int* __restrict__ dst,
                              const double* __restrict__ alpha, float* __restrict__ att)
{
  int e = blockIdx.x*256 + threadIdx.x;
  if (e >= NE) return;
  int s = src[e], d = dst[e];
  if (s == d) return;
  atomicAdd(&att[(size_t)s*NN + d], (float)alpha[e]);
}

// ---------------- f32 distance GEMM + fused per-tile top-12 -----------------
__global__ __launch_bounds__(256)
void dist32_k(const float* __restrict__ Z, const float* __restrict__ Znb,
              const float* __restrict__ sxA, const float* __restrict__ syA, const float* __restrict__ cjA,
              float* __restrict__ candV, int* __restrict__ candI)
{
  __shared__ __align__(16) char smem[34560];
  float (*lA)[33]    = (float(*)[33])(smem);
  float (*lB)[33]    = (float(*)[33])(smem + 8448);
  float (*stile)[129]= (float(*)[129])(smem);
  float* sSx = (float*)(smem + 33024);
  float* sSy = sSx + 128;
  float* sC  = sSy + 128;

  const int tid = threadIdx.x;
  const int m0 = blockIdx.y * 64;
  const int n0 = blockIdx.x * 128;
  const int tx = tid & 15;
  const int ty = tid >> 4;

  if (tid < 128){
    int jg = n0 + tid;
    if (jg < NN){ sSx[tid]=sxA[jg]; sSy[tid]=syA[jg]; sC[tid]=cjA[jg]; }
    else        { sSx[tid]=0.f; sSy[tid]=0.f; sC[tid]=-3e38f; }
  }

  float acc[4][8];
  #pragma unroll
  for (int i=0;i<4;i++)
    #pragma unroll
    for (int j=0;j<8;j++) acc[i][j] = 0.f;

  for (int kt = 0; kt < 8; kt++){
    const int k0 = kt << 5;
    __syncthreads();
    #pragma unroll
    for (int c=0;c<8;c++){
      int lin = tid + c*256;
      int row = lin >> 5, col = lin & 31;
      int gm = m0 + row;
      lA[row][col] = (gm < NN) ? Z[(size_t)gm*256 + k0 + col] : 0.f;
    }
    #pragma unroll
    for (int c=0;c<16;c++){
      int lin = tid + c*256;
      int row = lin >> 5, col = lin & 31;
      int gn = n0 + row;
      lB[row][col] = (gn < NN) ? Znb[(size_t)gn*256 + k0 + col] : 0.f;
    }
    __syncthreads();
    #pragma unroll 4
    for (int kk=0; kk<32; kk++){
      float a[4], b[8];
      #pragma unroll
      for (int i=0;i<4;i++) a[i] = lA[ty*4+i][kk];
      #pragma unroll
      for (int j=0;j<8;j++) b[j] = lB[tx*8+j][kk];
      #pragma unroll
      for (int i=0;i<4;i++)
        #pragma unroll
        for (int j=0;j<8;j++) acc[i][j] += a[i]*b[j];
    }
  }

  __syncthreads();
  #pragma unroll
  for (int i=0;i<4;i++)
    #pragma unroll
    for (int j=0;j<8;j++)
      stile[ty*4+i][tx*8+j] = acc[i][j];
  __syncthreads();

  if (tid < 64){
    const int gi = m0 + tid;
    if (gi < NN){
      float sxi = sxA[gi], syi = syA[gi];
      float tv[NCAND]; int ti[NCAND];
      #pragma unroll
      for (int p=0;p<NCAND;p++){ tv[p] = -3.4e38f; ti[p] = -1; }
      #pragma unroll 1
      for (int jj=0; jj<128; jj++){
        float s = 2.f*stile[tid][jj] + 2.f*(sxi*sSx[jj] + syi*sSy[jj]) + sC[jj];
        if (s > tv[NCAND-1]){
          bool g[NCAND];
          #pragma unroll
          for (int p=0;p<NCAND;p++) g[p] = s > tv[p];
          #pragma unroll
          for (int p=NCAND-1;p>0;--p) if (g[p-1]){ tv[p]=tv[p-1]; ti[p]=ti[p-1]; }
          #pragma unroll
          for (int p=0;p<NCAND;p++){ bool pl = g[p] && (p==0 || !g[p-1]); if (pl){ tv[p]=s; ti[p]=n0+jj; } }
        }
      }
      size_t base = ((size_t)gi*NTILE + blockIdx.x)*NCAND;
      #pragma unroll
      for (int p=0;p<NCAND;p++){ candV[base+p]=tv[p]; candI[base+p]=ti[p]; }
    }
  }
}

// ---------------- merge: f32 prefilter -> f64 wave rescore -> top-9 ---------
__global__ __launch_bounds__(256)
void merge64_k(const float* __restrict__ candV, const int* __restrict__ candI,
               const double* __restrict__ Z, const double* __restrict__ Znb,
               const double* __restrict__ sx64, const double* __restrict__ sy64,
               double* __restrict__ wgt9, int* __restrict__ idx9)
{
  __shared__ double zi[256];
  __shared__ float  fv[TCAND];
  __shared__ int    fj[TCAND];
  __shared__ float  tvs[PRE];
  __shared__ int    pj[PRE];
  __shared__ double ps[PRE];
  __shared__ double tv9[9];
  __shared__ int    ti9[9];

  const int i = blockIdx.x;
  const int t = threadIdx.x;
  zi[t] = Z[(size_t)i*256 + t];
  for (int c = t; c < TCAND; c += 256){
    fv[c] = candV[(size_t)i*TCAND + c];
    fj[c] = candI[(size_t)i*TCAND + c];
  }
  __syncthreads();

  if (t == 0){
    for (int p=0;p<PRE;p++){ tvs[p]=-3.4e38f; pj[p]=-1; }
    for (int c=0;c<TCAND;c++){
      float s = fv[c];
      if (!(s > tvs[PRE-1])) continue;
      int j = fj[c];
      if (j < 0) continue;
      int p = PRE-1;
      while (p > 0 && s > tvs[p-1]){ tvs[p]=tvs[p-1]; pj[p]=pj[p-1]; --p; }
      tvs[p]=s; pj[p]=j;
    }
  }
  __syncthreads();

  const int wv = t >> 6, lane = t & 63;
  const double sxi = sx64[i], syi = sy64[i];
  for (int c = wv; c < PRE; c += 4){
    int j = pj[c];
    double s = -1.0e300;
    if (j >= 0){
      const double* zj = Znb + (size_t)j*256;
      double p = 0.0;
      #pragma unroll
      for (int u=0;u<4;u++){
        double b = zj[lane + 64*u];
        double a = zi[lane + 64*u];
        p = fma(2.0*a - b, b, p);     // += 2ab - b^2
      }
      #pragma unroll
      for (int off=32; off; off>>=1) p += __shfl_xor(p, off);
      double sxj = sx64[j], syj = sy64[j];
      s = p + 2.0*(sxi*sxj + syi*syj) - (sxj*sxj + syj*syj);
    }
    if (lane == 0) ps[c] = s;
  }
  __syncthreads();

  if (t == 0){
    for (int p=0;p<9;p++){ tv9[p]=-1.0e301; ti9[p]=0x7FFFFFFF; }
    for (int c=0;c<PRE;c++){
      double s = ps[c]; int j = pj[c];
      if (j < 0 || s < -1.0e299) continue;
      if (!((s > tv9[8]) || (s == tv9[8] && j < ti9[8]))) continue;
      int p = 8;
      while (p > 0 && ((s > tv9[p-1]) || (s == tv9[p-1] && j < ti9[p-1]))){
        tv9[p]=tv9[p-1]; ti9[p]=ti9[p-1]; --p;
      }
      tv9[p]=s; ti9[p]=j;
    }
    double m = tv9[0], e[9], S=0.0;
    for (int k=0;k<9;k++){ e[k]=exp(tv9[k]-m); S+=e[k]; }
    for (int k=0;k<9;k++){
      wgt9[(size_t)i*9+k] = e[k]/S;
      idx9[(size_t)i*9+k] = ti9[k];
    }
  }
}

// ---------------- znb prep + casts ------------------------------------------
__global__ __launch_bounds__(256)
void znbprep_k(const double* __restrict__ znb, const double* __restrict__ ssq64,
               float* __restrict__ cjA)
{
  __shared__ double red[256];
  int i = blockIdx.x, d = threadIdx.x;
  double v = znb[(size_t)i*256 + d];
  red[d] = v*v;
  __syncthreads();
  for (int s=128; s; s>>=1){ if (d<s) red[d]+=red[d+s]; __syncthreads(); }
  if (d==0) cjA[i] = -(float)(red[0] + ssq64[i]);
}
__global__ void castz_k(const double* __restrict__ z64, float* __restrict__ z32, int n){
  int t = blockIdx.x*256+threadIdx.x;
  if (t < n) z32[t] = (float)z64[t];
}
__global__ void featout_k(const double* __restrict__ z, float* __restrict__ o){
  int t = blockIdx.x*256+threadIdx.x;
  if (t < NN*128){ int i=t>>7, d=t&127; o[t] = (float)z[(size_t)i*256 + d]; }
}

__global__ __launch_bounds__(256)
void zout_k(const double* __restrict__ Z, const double* __restrict__ Znb,
            const int* __restrict__ idx9, const double* __restrict__ wgt9,
            float* __restrict__ zoOut, float* __restrict__ zoF32, float* __restrict__ x1)
{
  int i = blockIdx.x; int d = threadIdx.x;
  double a = Z[(size_t)i*256 + d];
  #pragma unroll
  for (int k=0;k<9;k++){
    int j = idx9[(size_t)i*9+k];
    double w = wgt9[(size_t)i*9+k];
    double t = w * Znb[(size_t)j*256 + d];
    a += t;
    x1[((size_t)i*9+k)*256 + d] = (float)t;
  }
  float af = (float)a;
  zoOut[(size_t)i*256+d] = af;
  zoF32[(size_t)i*256+d] = af;
}

__global__ __launch_bounds__(256)
void q_k(const float* __restrict__ zoF, const float* __restrict__ clus, float* __restrict__ qB)
{
  __shared__ float wred[10][4];
  __shared__ float qs[10];
  int i = blockIdx.x, d = threadIdx.x;
  int lane = d & 63, wv = d >> 6;
  float zo = zoF[(size_t)i*256 + d];
  #pragma unroll
  for (int c=0;c<10;c++){
    float df = zo - clus[(size_t)c*256 + d];
    float p = df*df;
    #pragma unroll
    for (int off=32; off; off>>=1) p += __shfl_down(p, off);
    if (lane == 0) wred[c][wv] = p;
  }
  __syncthreads();
  if (d < 10){
    float d2 = wred[d][0]+wred[d][1]+wred[d][2]+wred[d][3];
    qs[d] = 1.f/(1.f + d2);
  }
  __syncthreads();
  if (d < 10){
    float s = 0.f;
    #pragma unroll
    for (int c=0;c<10;c++) s += qs[c];
    qB[(size_t)i*10 + d] = qs[d]/s;
  }
}

// ---------------- host ------------------------------------------------------
extern "C" void kernel_launch(void* const* d_in, const int* in_sizes, int n_in,
                              void* d_out, int out_size, void* d_ws, size_t ws_size,
                              hipStream_t stream)
{
  (void)in_sizes; (void)n_in; (void)out_size; (void)ws_size;
  const float* x    = (const float*)d_in[0];
  const float* xnb  = (const float*)d_in[1];
  const float* spat = (const float*)d_in[2];
  const int*   adj  = (const int*)d_in[3];
  const int*   adjp = (const int*)d_in[4];
  const float* W1   = (const float*)d_in[5];
  const float* b1   = (const float*)d_in[6];
  const float* g1   = (const float*)d_in[7];
  const float* be1  = (const float*)d_in[8];
  const float* W2   = (const float*)d_in[9];
  const float* b2   = (const float*)d_in[10];
  const float* g2   = (const float*)d_in[11];
  const float* be2  = (const float*)d_in[12];
  const float* Wq   = (const float*)d_in[13];
  const float* Wk   = (const float*)d_in[14];
  const float* Wv   = (const float*)d_in[15];
  const float* Wsm  = (const float*)d_in[16];
  const float* bq   = (const float*)d_in[17];
  const float* bk   = (const float*)d_in[18];
  const float* bv   = (const float*)d_in[19];
  const float* bs   = (const float*)d_in[20];
  const float* decW = (const float*)d_in[21];
  const float* decb = (const float*)d_in[22];
  const float* decg = (const float*)d_in[23];
  const float* decbe= (const float*)d_in[24];
  const float* clus = (const float*)d_in[25];
  float* outF = (float*)d_out;
  const int* srcA = adj,  *dstA = adj + NE;
  const int* srcP = adjp, *dstP = adjp + NE;

  char* wsb = (char*)d_ws;
  size_t off = 0;
  auto alloc = [&](size_t bytes)->char*{
    char* p = wsb + off;
    off = (off + bytes + 255) & ~(size_t)255;
    return p;
  };
  double* W1t  = (double*)alloc(768000*8);
  double* W2t  = (double*)alloc(32768*8);
  double* Bct  = (double*)alloc(196608*8);
  float*  Dt   = (float*) alloc(768000*4);
  double* bcat = (double*)alloc(1536*8);
  double* sx64 = (double*)alloc(NN*8);
  double* sy64 = (double*)alloc(NN*8);
  double* ssq64= (double*)alloc(NN*8);
  float*  sx32 = (float*) alloc(NN*4);
  float*  sy32 = (float*) alloc(NN*4);
  double* b1c  = (double*)alloc(256*8);
  double* b2c  = (double*)alloc(128*8);
  double* H1   = (double*)alloc((size_t)NN*256*8);
  double* zX64 = (double*)alloc((size_t)NN*256*8);
  double* zNB64= (double*)alloc((size_t)NN*256*8);
  double* hcur = (double*)alloc((size_t)NN*128*8);
  double* QK1  = (double*)alloc((size_t)NN*512*8);
  double* QK2  = (double*)alloc((size_t)NN*512*8);
  double* alphaA=(double*)alloc((size_t)NE*8);
  double* alphaP=(double*)alloc((size_t)NE*8);
  double* part = (double*)alloc((size_t)4*NN*256*8);   // split-K partials (49 MB)
  // CSRs
  int* rpDA = (int*)alloc((NN+1)*4);
  int* rpDP = (int*)alloc((NN+1)*4);
  int* rpSA = (int*)alloc((NN+1)*4);
  int* rpSP = (int*)alloc((NN+1)*4);
  int* curDA= (int*)alloc(NN*4);
  int* curDP= (int*)alloc(NN*4);
  int* curSA= (int*)alloc(NN*4);
  int* curSP= (int*)alloc(NN*4);
  int* elDA = (int*)alloc(NE*4);
  int* elDP = (int*)alloc(NE*4);
  int* elSA = (int*)alloc(NE*4);
  int* elSP = (int*)alloc(NE*4);
  float*  zX32 = (float*) alloc((size_t)NN*256*4);
  float*  zNB32= (float*) alloc((size_t)NN*256*4);
  float*  cjA  = (float*) alloc(NN*4);
  float*  candV= (float*) alloc((size_t)NN*TCAND*4);
  int*    candI= (int*)   alloc((size_t)NN*TCAND*4);
  int*    idx9 = (int*)   alloc((size_t)NN*9*4);
  double* wgt9 = (double*)alloc((size_t)NN*9*8);
  float*  zoF32= (float*) alloc((size_t)NN*256*4);

  prep_k<<<6926, 256, 0, stream>>>(W1, W2, Wq, Wk, Wv, Wsm, bq, bk, bv, bs, decW, spat,
                                   W1t, W2t, Bct, Dt, bcat,
                                   sx64, sy64, ssq64, sx32, sy32);
  castup_k<<<1, 256, 0, stream>>>(b1, b1c, 256);
  castup_k<<<1, 256, 0, stream>>>(b2, b2c, 128);

  // CSR build (4 CSRs)
  hipMemsetAsync(curDA, 0, NN*4, stream);
  hipMemsetAsync(curDP, 0, NN*4, stream);
  hipMemsetAsync(curSA, 0, NN*4, stream);
  hipMemsetAsync(curSP, 0, NN*4, stream);
  csr_cnt_k<<<375, 256, 0, stream>>>(dstA, curDA);
  csr_cnt_k<<<375, 256, 0, stream>>>(dstP, curDP);
  csr_cnt_k<<<375, 256, 0, stream>>>(srcA, curSA);
  csr_cnt_k<<<375, 256, 0, stream>>>(srcP, curSP);
  csr_scan_k<<<1, 256, 0, stream>>>(curDA, rpDA, curDA);
  csr_scan_k<<<1, 256, 0, stream>>>(curDP, rpDP, curDP);
  csr_scan_k<<<1, 256, 0, stream>>>(curSA, rpSA, curSA);
  csr_scan_k<<<1, 256, 0, stream>>>(curSP, rpSP, curSP);
  csr_fill_k<<<375, 256, 0, stream>>>(dstA, curDA, elDA);
  csr_fill_k<<<375, 256, 0, stream>>>(dstP, curDP, elDP);
  csr_fill_k<<<375, 256, 0, stream>>>(srcA, curSA, elSA);
  csr_fill_k<<<375, 256, 0, stream>>>(srcP, curSP, elSP);

  auto enc = [&](const float* xin, double* zbuf, bool isX){
    // encoder GEMM 1: split-K (4 x 768)
    gemm64s_k<float><<<dim3(4,94,4), 256, 0, stream>>>(xin, KDIN, W1t, KDIN,
                                                       NN, KDIN, 768, 256, part);
    epi64_k<<<(NN*256+255)/256, 256, 0, stream>>>(part, 4, (size_t)NN*256,
                                                  NN, 256, b1c, g1, be1, H1, 256);
    // encoder GEMM 2: split-K (4 x 64)
    gemm64s_k<double><<<dim3(2,94,4), 256, 0, stream>>>(H1, 256, W2t, 256,
                                                        NN, 256, 64, 128, part);
    epi64_k<<<(NN*128+255)/256, 256, 0, stream>>>(part, 4, (size_t)NN*128,
                                                  NN, 128, b2c, g2, be2, zbuf, 256);
    const double* hin = zbuf; int ldh = 256;
    for (int l=0; l<3; l++){
      const double* Bh = Bct + (size_t)l*65536;
      const double* bc = bcat + l*512;
      if (l != 1){
        gemm64_k<0,double><<<dim3(8,94), 256, 0, stream>>>(hin, ldh, Bh, 128, NN, 128, 512,
                                                           QK1, 512, bc, nullptr, nullptr, QK2);
        attn_k<<<1500, 256, 0, stream>>>(QK1, rpDA, elDA, srcA, alphaA);
        attn_k<<<1500, 256, 0, stream>>>(QK2, rpDP, elDP, srcP, alphaP);
      } else {
        gemm64_k<0,double><<<dim3(8,94), 256, 0, stream>>>(hin, ldh, Bh, 128, NN, 128, 512,
                                                           QK1, 512, bc, nullptr, nullptr, nullptr);
        attn_k<<<1500, 256, 0, stream>>>(QK1, rpDA, elDA, srcA, alphaA);
        gemm64_k<0,double><<<dim3(8,94), 256, 0, stream>>>(QK1 + 384, 512, Bh, 128, NN, 128, 512,
                                                           QK2, 512, bc, nullptr, nullptr, nullptr);
        attn_k<<<1500, 256, 0, stream>>>(QK2, rpDP, elDP, srcP, alphaP);
      }
      if (isX && l == 2){
        hipMemsetAsync(outF + (size_t)OFF_ATT, 0, (size_t)NN*NN*4, stream);
        att_scatter_k<<<375, 256, 0, stream>>>(srcP, dstP, alphaP, outF + (size_t)OFF_ATT);
      }
      if (l < 2){
        spmm_csr_k<<<1500, 256, 0, stream>>>(QK1, QK2, rpSA, elSA, dstA, alphaA,
                                             rpSP, elSP, dstP, alphaP, hcur, 128, 0, 1);
        hin = hcur; ldh = 128;
      } else {
        spmm_csr_k<<<1500, 256, 0, stream>>>(QK1, QK2, rpSA, elSA, dstA, alphaA,
                                             rpSP, elSP, dstP, alphaP, zbuf, 256, 128, 0);
      }
    }
  };
  enc(x,   zX64,  true);
  enc(xnb, zNB64, false);

  castz_k<<<6000, 256, 0, stream>>>(zX64,  zX32,  NN*256);
  castz_k<<<6000, 256, 0, stream>>>(zNB64, zNB32, NN*256);
  znbprep_k<<<NN, 256, 0, stream>>>(zNB64, ssq64, cjA);
  dist32_k<<<dim3(NTILE,94), 256, 0, stream>>>(zX32, zNB32, sx32, sy32, cjA, candV, candI);
  merge64_k<<<NN, 256, 0, stream>>>(candV, candI, zX64, zNB64, sx64, sy64, wgt9, idx9);

  zout_k<<<NN, 256, 0, stream>>>(zX64, zNB64, idx9, wgt9,
                                 outF + (size_t)OFF_ZOUT, zoF32, outF + (size_t)OFF_X1);
  gemm32d_k<<<dim3(47,94), 256, 0, stream>>>(zoF32, 256, Dt, 256, NN, 256, 3000,
                                             outF + (size_t)OFF_DE1, 3000, decb, decg, decbe,
                                             outF + (size_t)OFF_DE2);
  q_k<<<NN, 256, 0, stream>>>(zoF32, clus, outF + (size_t)OFF_Q);
  featout_k<<<3000, 256, 0, stream>>>(zX64, outF + (size_t)OFF_FEAT);
}

// Round 11
// 3522.014 us; speedup vs baseline: 2.0355x; 1.0954x over previous
//
#include <hip/hip_runtime.h>
#include <hip/hip_bf16.h>
#include <math.h>
#include <stdint.h>

#define NN 6000
#define NE 96000
#define KDIN 3000
#define NCAND 12            // candidates per 128-col tile
#define NTILE 47
#define TCAND (NCAND*NTILE) // 564 per row
#define PRE 32              // f64-rescored candidates per row

// output element offsets (d_out is FLOAT32)
#define OFF_ZOUT 0
#define OFF_DE1  1536000
#define OFF_Q    19536000
#define OFF_FEAT 19596000
#define OFF_DE2  20364000
#define OFF_X1   38364000
#define OFF_ATT  52188000

// ---------------- weight prep: transpose, cast to f64 -----------------------
__global__ void prep_k(const float* __restrict__ W1, const float* __restrict__ W2,
                       const float* __restrict__ Wq, const float* __restrict__ Wk,
                       const float* __restrict__ Wv, const float* __restrict__ Ws,
                       const float* __restrict__ bq, const float* __restrict__ bk,
                       const float* __restrict__ bv, const float* __restrict__ bs,
                       const float* __restrict__ decW, const float* __restrict__ spat,
                       double* __restrict__ W1t, double* __restrict__ W2t,
                       double* __restrict__ Bct, float* __restrict__ Dt,
                       double* __restrict__ bcat,
                       double* __restrict__ sx64, double* __restrict__ sy64,
                       double* __restrict__ ssq64,
                       float* __restrict__ sx32, float* __restrict__ sy32)
{
  int t = blockIdx.x * 256 + threadIdx.x;
  if (t < 768000){
    int n = t / 3000, k = t % 3000;
    W1t[t] = (double)W1[(size_t)k * 256 + n]; return;
  }
  t -= 768000;
  if (t < 32768){
    int n = t / 256, k = t % 256;
    W2t[t] = (double)W2[(size_t)k * 128 + n]; return;
  }
  t -= 32768;
  if (t < 196608){
    int l = t / 65536; int rem = t % 65536;
    int n = rem / 128, k = rem % 128;
    int sel = n >> 7, nn = n & 127;
    const float* Wm = sel==0 ? Wq : sel==1 ? Wk : sel==2 ? Wv : Ws;
    Bct[t] = (double)Wm[((size_t)(l*128) + k) * 128 + nn]; return;
  }
  t -= 196608;
  if (t < 768000){
    int n = t / 256, k = t % 256;
    Dt[t] = decW[(size_t)k * 3000 + n]; return;
  }
  t -= 768000;
  if (t < 1536){
    int l = t / 512, n = t % 512;
    int sel = n >> 7, nn = n & 127;
    const float* bm = sel==0 ? bq : sel==1 ? bk : sel==2 ? bv : bs;
    bcat[t] = (double)bm[l*128 + nn]; return;
  }
  t -= 1536;
  if (t < NN){
    float sx = spat[(size_t)t*2], sy = spat[(size_t)t*2+1];
    sx64[t]=(double)sx; sy64[t]=(double)sy;
    ssq64[t]=(double)sx*(double)sx + (double)sy*(double)sy;
    sx32[t]=sx; sy32[t]=sy; return;
  }
}

__global__ void castup_k(const float* __restrict__ s, double* __restrict__ d, int n){
  int t = blockIdx.x*256 + threadIdx.x;
  if (t < n) d[t] = (double)s[t];
}

// ---------------- f64 vector GEMM, NT, 64x64, conflict-free frags -----------
template<int EPI, typename TA>
__global__ __launch_bounds__(256)
void gemm64_k(const TA* __restrict__ A, int lda,
              const double* __restrict__ Bt, int ldb,
              int M, int K, int Ncol,
              double* __restrict__ outF, int ldc,
              const double* __restrict__ bias,
              const float* __restrict__ gam, const float* __restrict__ bet,
              double* __restrict__ outF2)
{
  __shared__ double lA[64][33];
  __shared__ double lB[64][33];
  const int tid = threadIdx.x;
  const int m0 = blockIdx.y * 64;
  const int n0 = blockIdx.x * 64;
  const int tx = tid & 15;
  const int ty = tid >> 4;

  double acc[4][4];
  #pragma unroll
  for (int i=0;i<4;i++)
    #pragma unroll
    for (int j=0;j<4;j++) acc[i][j] = 0.0;

  const int nkt = (K + 31) >> 5;
  for (int kt = 0; kt < nkt; kt++){
    const int k0 = kt << 5;
    __syncthreads();
    #pragma unroll
    for (int c=0;c<8;c++){
      int lin = tid + c*256;
      int row = lin >> 5, col = lin & 31;
      int gm = m0 + row, gk = k0 + col;
      double va = 0.0, vb = 0.0;
      if (gm < M && gk < K)        va = (double)A [(size_t)gm*lda + gk];
      if (n0+row < Ncol && gk < K) vb = Bt[(size_t)(n0+row)*ldb + gk];
      lA[row][col] = va;
      lB[row][col] = vb;
    }
    __syncthreads();
    #pragma unroll 2
    for (int kk=0; kk<32; kk++){
      double a0=lA[ty][kk], a1=lA[ty+16][kk], a2=lA[ty+32][kk], a3=lA[ty+48][kk];
      double b0=lB[tx][kk], b1=lB[tx+16][kk], b2=lB[tx+32][kk], b3=lB[tx+48][kk];
      acc[0][0]+=a0*b0; acc[0][1]+=a0*b1; acc[0][2]+=a0*b2; acc[0][3]+=a0*b3;
      acc[1][0]+=a1*b0; acc[1][1]+=a1*b1; acc[1][2]+=a1*b2; acc[1][3]+=a1*b3;
      acc[2][0]+=a2*b0; acc[2][1]+=a2*b1; acc[2][2]+=a2*b2; acc[2][3]+=a2*b3;
      acc[3][0]+=a3*b0; acc[3][1]+=a3*b1; acc[3][2]+=a3*b2; acc[3][3]+=a3*b3;
    }
  }
  #pragma unroll
  for (int j=0;j<4;j++){
    int gn = n0 + tx + 16*j;
    if (gn >= Ncol) continue;
    double bi = bias[gn];
    #pragma unroll
    for (int i=0;i<4;i++){
      int gm = m0 + ty + 16*i;
      if (gm >= M) continue;
      double v = acc[i][j] + bi;
      outF[(size_t)gm*ldc + gn] = v;
      if (outF2) outF2[(size_t)gm*ldc + gn] = v;
    }
  }
}

// ---------------- split-K f64 GEMM: partial per blockIdx.z ------------------
template<typename TA>
__global__ __launch_bounds__(256)
void gemm64s_k(const TA* __restrict__ A, int lda,
               const double* __restrict__ Bt, int ldb,
               int M, int K, int kchunk, int Ncol,
               double* __restrict__ part)   // [z][M*Ncol]
{
  __shared__ double lA[64][33];
  __shared__ double lB[64][33];
  const int tid = threadIdx.x;
  const int m0 = blockIdx.y * 64;
  const int n0 = blockIdx.x * 64;
  const int tx = tid & 15;
  const int ty = tid >> 4;
  const int kbeg = blockIdx.z * kchunk;
  const int kend = min(K, kbeg + kchunk);
  double* dst = part + (size_t)blockIdx.z * M * Ncol;

  double acc[4][4];
  #pragma unroll
  for (int i=0;i<4;i++)
    #pragma unroll
    for (int j=0;j<4;j++) acc[i][j] = 0.0;

  const int nkt = (kend - kbeg + 31) >> 5;
  for (int kt = 0; kt < nkt; kt++){
    const int k0 = kbeg + (kt << 5);
    __syncthreads();
    #pragma unroll
    for (int c=0;c<8;c++){
      int lin = tid + c*256;
      int row = lin >> 5, col = lin & 31;
      int gm = m0 + row, gk = k0 + col;
      double va = 0.0, vb = 0.0;
      if (gm < M && gk < kend)        va = (double)A [(size_t)gm*lda + gk];
      if (n0+row < Ncol && gk < kend) vb = Bt[(size_t)(n0+row)*ldb + gk];
      lA[row][col] = va;
      lB[row][col] = vb;
    }
    __syncthreads();
    #pragma unroll 2
    for (int kk=0; kk<32; kk++){
      double a0=lA[ty][kk], a1=lA[ty+16][kk], a2=lA[ty+32][kk], a3=lA[ty+48][kk];
      double b0=lB[tx][kk], b1=lB[tx+16][kk], b2=lB[tx+32][kk], b3=lB[tx+48][kk];
      acc[0][0]+=a0*b0; acc[0][1]+=a0*b1; acc[0][2]+=a0*b2; acc[0][3]+=a0*b3;
      acc[1][0]+=a1*b0; acc[1][1]+=a1*b1; acc[1][2]+=a1*b2; acc[1][3]+=a1*b3;
      acc[2][0]+=a2*b0; acc[2][1]+=a2*b1; acc[2][2]+=a2*b2; acc[2][3]+=a2*b3;
      acc[3][0]+=a3*b0; acc[3][1]+=a3*b1; acc[3][2]+=a3*b2; acc[3][3]+=a3*b3;
    }
  }
  #pragma unroll
  for (int j=0;j<4;j++){
    int gn = n0 + tx + 16*j;
    if (gn >= Ncol) continue;
    #pragma unroll
    for (int i=0;i<4;i++){
      int gm = m0 + ty + 16*i;
      if (gm >= M) continue;
      dst[(size_t)gm*Ncol + gn] = acc[i][j];
    }
  }
}

// reduce partials + bias + BN + ELU -> out (f64)
__global__ void epi64_k(const double* __restrict__ part, int nsplit, size_t pstride,
                        int M, int Ncol, const double* __restrict__ bias,
                        const float* __restrict__ gam, const float* __restrict__ bet,
                        double* __restrict__ out, int ldo)
{
  int t = blockIdx.x*256 + threadIdx.x;
  if (t >= M*Ncol) return;
  int gm = t / Ncol, gn = t - gm*Ncol;
  double v = 0.0;
  for (int s=0; s<nsplit; s++) v += part[(size_t)s*pstride + t];
  const double BNS = 0.99995000374968755261;
  v += bias[gn];
  v = v * ((double)gam[gn]*BNS) + (double)bet[gn];
  v = v > 0.0 ? v : expm1(v);
  out[(size_t)gm*ldo + gn] = v;
}

// ---------------- f32 GEMM (decoder, elu-bn to two f32 outs) ----------------
__global__ __launch_bounds__(256)
void gemm32d_k(const float* __restrict__ A, int lda,
               const float* __restrict__ Bt, int ldb,
               int M, int K, int Ncol,
               float* __restrict__ out1, int ldc,
               const float* __restrict__ bias, const float* __restrict__ gam,
               const float* __restrict__ bet, float* __restrict__ out2)
{
  __shared__ float lA[64][33];
  __shared__ float lB[64][33];
  const int tid = threadIdx.x;
  const int m0 = blockIdx.y * 64;
  const int n0 = blockIdx.x * 64;
  const int tx = tid & 15;
  const int ty = tid >> 4;

  float acc[4][4];
  #pragma unroll
  for (int i=0;i<4;i++)
    #pragma unroll
    for (int j=0;j<4;j++) acc[i][j] = 0.f;

  const int nkt = (K + 31) >> 5;
  for (int kt = 0; kt < nkt; kt++){
    const int k0 = kt << 5;
    __syncthreads();
    #pragma unroll
    for (int c=0;c<8;c++){
      int lin = tid + c*256;
      int row = lin >> 5, col = lin & 31;
      int gm = m0 + row, gk = k0 + col;
      float va = 0.f, vb = 0.f;
      if (gm < M && gk < K)        va = A [(size_t)gm*lda + gk];
      if (n0+row < Ncol && gk < K) vb = Bt[(size_t)(n0+row)*ldb + gk];
      lA[row][col] = va;
      lB[row][col] = vb;
    }
    __syncthreads();
    #pragma unroll 4
    for (int kk=0; kk<32; kk++){
      float a0=lA[ty][kk], a1=lA[ty+16][kk], a2=lA[ty+32][kk], a3=lA[ty+48][kk];
      float b0=lB[tx][kk], b1=lB[tx+16][kk], b2=lB[tx+32][kk], b3=lB[tx+48][kk];
      acc[0][0]+=a0*b0; acc[0][1]+=a0*b1; acc[0][2]+=a0*b2; acc[0][3]+=a0*b3;
      acc[1][0]+=a1*b0; acc[1][1]+=a1*b1; acc[1][2]+=a1*b2; acc[1][3]+=a1*b3;
      acc[2][0]+=a2*b0; acc[2][1]+=a2*b1; acc[2][2]+=a2*b2; acc[2][3]+=a2*b3;
      acc[3][0]+=a3*b0; acc[3][1]+=a3*b1; acc[3][2]+=a3*b2; acc[3][3]+=a3*b3;
    }
  }
  const float BNS = 0.99995000374968755f;
  #pragma unroll
  for (int j=0;j<4;j++){
    int gn = n0 + tx + 16*j;
    if (gn >= Ncol) continue;
    float bi = bias[gn];
    float gs = gam[gn]*BNS, be = bet[gn];
    #pragma unroll
    for (int i=0;i<4;i++){
      int gm = m0 + ty + 16*i;
      if (gm >= M) continue;
      float v = acc[i][j] + bi;
      v = v*gs + be; v = v > 0.f ? v : expm1f(v);
      out1[(size_t)gm*ldc + gn] = v;
      out2[(size_t)gm*ldc + gn] = v;
    }
  }
}

// ---------------- CSR build --------------------------------------------------
__global__ void csr_cnt_k(const int* __restrict__ key, int* __restrict__ cnt){
  int e = blockIdx.x*256 + threadIdx.x;
  if (e < NE) atomicAdd(&cnt[key[e]], 1);
}
__global__ __launch_bounds__(256)
void csr_scan_k(const int* __restrict__ cnt, int* __restrict__ rowptr, int* __restrict__ cursor){
  __shared__ int part[256];
  int t = threadIdx.x;
  int base = t*24;
  int loc[24]; int s=0;
  #pragma unroll
  for (int u=0;u<24;u++){
    int idx = base+u;
    int v = (idx<NN) ? cnt[idx] : 0;
    loc[u] = s; s += v;
  }
  part[t] = s;
  __syncthreads();
  if (t==0){
    int run=0;
    for (int u=0;u<256;u++){ int tmp=part[u]; part[u]=run; run+=tmp; }
  }
  __syncthreads();
  int off = part[t];
  #pragma unroll
  for (int u=0;u<24;u++){
    int idx = base+u;
    if (idx<NN){ rowptr[idx]=off+loc[u]; cursor[idx]=off+loc[u]; }
  }
  if (t==255) rowptr[NN] = off + s;
}
__global__ void csr_fill_k(const int* __restrict__ key, int* __restrict__ cursor,
                           int* __restrict__ elist){
  int e = blockIdx.x*256 + threadIdx.x;
  if (e < NE){ int pos = atomicAdd(&cursor[key[e]], 1); elist[pos] = e; }
}

// ---------------- fused per-node attention (dst-CSR, no atomics) ------------
__global__ __launch_bounds__(256)
void attn_k(double* __restrict__ QKVS, const int* __restrict__ rowptr,
            const int* __restrict__ elist, const int* __restrict__ src,
            double* __restrict__ alpha)
{
  __shared__ double lg[4][128];
  const int w = threadIdx.x >> 6;
  const int node = blockIdx.x*4 + w;
  if (node >= NN) return;
  const int lane = threadIdx.x & 63;
  const int e0 = rowptr[node], e1 = rowptr[node+1];
  const int deg = e1 - e0;
  if (deg <= 0) return;
  const double SC = 0.088388347648318447; // 1/sqrt(128)
  const double* q = QKVS + (size_t)node*512;
  double q0 = q[lane], q1 = q[lane+64];

  if (deg <= 128){
    double m = -1.0e300;
    for (int i=0;i<deg;i++){
      const double* k = QKVS + (size_t)src[elist[e0+i]]*512 + 128;
      double p = q0*k[lane] + q1*k[lane+64];
      #pragma unroll
      for (int off=32; off; off>>=1) p += __shfl_xor(p, off);
      p *= SC;
      if (lane==0) lg[w][i] = p;
      m = fmax(m, p);
    }
    double S = 0.0;
    for (int i=0;i<deg;i++){
      double ex = exp(lg[w][i] - m);
      if (lane==0) lg[w][i] = ex;
      S += ex;
    }
    double inv = 1.0 / S;
    double o0 = QKVS[(size_t)node*512 + 384 + lane];
    double o1 = QKVS[(size_t)node*512 + 448 + lane];
    for (int i=0;i<deg;i++){
      int e = elist[e0+i];
      double a = lg[w][i] * inv;
      const double* v = QKVS + (size_t)src[e]*512 + 256;
      o0 = fma(a, v[lane],    o0);
      o1 = fma(a, v[lane+64], o1);
      if (lane==0) alpha[e] = a;
    }
    QKVS[(size_t)node*512 + 384 + lane] = o0;
    QKVS[(size_t)node*512 + 448 + lane] = o1;
  } else {
    double m = -1.0e300;
    for (int i=0;i<deg;i++){
      const double* k = QKVS + (size_t)src[elist[e0+i]]*512 + 128;
      double p = q0*k[lane] + q1*k[lane+64];
      #pragma unroll
      for (int off=32; off; off>>=1) p += __shfl_xor(p, off);
      m = fmax(m, p*SC);
    }
    double S = 0.0;
    for (int i=0;i<deg;i++){
      const double* k = QKVS + (size_t)src[elist[e0+i]]*512 + 128;
      double p = q0*k[lane] + q1*k[lane+64];
      #pragma unroll
      for (int off=32; off; off>>=1) p += __shfl_xor(p, off);
      S += exp(p*SC - m);
    }
    double inv = 1.0 / S;
    double o0 = QKVS[(size_t)node*512 + 384 + lane];
    double o1 = QKVS[(size_t)node*512 + 448 + lane];
    for (int i=0;i<deg;i++){
      int e = elist[e0+i];
      const double* k = QKVS + (size_t)src[e]*512 + 128;
      double p = q0*k[lane] + q1*k[lane+64];
      #pragma unroll
      for (int off=32; off; off>>=1) p += __shfl_xor(p, off);
      double a = exp(p*SC - m) * inv;
      const double* v = QKVS + (size_t)src[e]*512 + 256;
      o0 = fma(a, v[lane],    o0);
      o1 = fma(a, v[lane+64], o1);
      if (lane==0) alpha[e] = a;
    }
    QKVS[(size_t)node*512 + 384 + lane] = o0;
    QKVS[(size_t)node*512 + 448 + lane] = o1;
  }
}

// ---------------- fused spmm over src-CSR (both graphs, no atomics) ---------
__global__ __launch_bounds__(256)
void spmm_csr_k(const double* __restrict__ QK1, const double* __restrict__ QK2,
                const int* __restrict__ rpSA, const int* __restrict__ elSA,
                const int* __restrict__ dstA, const double* __restrict__ aA,
                const int* __restrict__ rpSP, const int* __restrict__ elSP,
                const int* __restrict__ dstP, const double* __restrict__ aP,
                double* __restrict__ out, int ldo, int offo, int dorelu)
{
  const int node = blockIdx.x*4 + (threadIdx.x>>6);
  if (node >= NN) return;
  const int lane = threadIdx.x & 63;
  double a0 = 0.0, a1 = 0.0;
  for (int idx = rpSA[node]; idx < rpSA[node+1]; ++idx){
    int e = elSA[idx]; int d = dstA[e];
    if (d != node){
      double wgt = 0.5 * aA[e];
      const double* o = QK1 + (size_t)d*512 + 384;
      a0 = fma(wgt, o[lane],    a0);
      a1 = fma(wgt, o[lane+64], a1);
    }
  }
  for (int idx = rpSP[node]; idx < rpSP[node+1]; ++idx){
    int e = elSP[idx]; int d = dstP[e];
    if (d != node){
      double wgt = 0.5 * aP[e];
      const double* o = QK2 + (size_t)d*512 + 384;
      a0 = fma(wgt, o[lane],    a0);
      a1 = fma(wgt, o[lane+64], a1);
    }
  }
  if (dorelu){ a0 = fmax(a0, 0.0); a1 = fmax(a1, 0.0); }
  out[(size_t)node*ldo + offo + lane]      = a0;
  out[(size_t)node*ldo + offo + 64 + lane] = a1;
}

__global__ void att_scatter_k(const int* __restrict__ src, const int* __restrict__ dst,
                              const double* __restrict__ alpha, float* __restrict__ att)
{
  int e = blockIdx.x*256 + threadIdx.x;
  if (e >= NE) return;
  int s = src[e], d = dst[e];
  if (s == d) return;
  atomicAdd(&att[(size_t)s*NN + d], (float)alpha[e]);
}

// ---------------- f32 distance GEMM + fused per-tile top-12 -----------------
// conflict-free fragment map (row = ty+16i / tx+16j), float4 LDS, pad 36
__global__ __launch_bounds__(256)
void dist32_k(const float* __restrict__ Z, const float* __restrict__ Znb,
              const float* __restrict__ sxA, const float* __restrict__ syA, const float* __restrict__ cjA,
              float* __restrict__ candV, int* __restrict__ candI)
{
  __shared__ __align__(16) char smem[33024 + 1536];
  float (*lA)[36]    = (float(*)[36])(smem);            // 64x36 = 9216B
  float (*lB)[36]    = (float(*)[36])(smem + 9216);     // 128x36 = 18432B
  float (*stile)[129]= (float(*)[129])(smem);           // 64x129 = 33024B (overlay)
  float* sSx = (float*)(smem + 33024);
  float* sSy = sSx + 128;
  float* sC  = sSy + 128;

  const int tid = threadIdx.x;
  const int m0 = blockIdx.y * 64;
  const int n0 = blockIdx.x * 128;
  const int tx = tid & 15;
  const int ty = tid >> 4;

  if (tid < 128){
    int jg = n0 + tid;
    if (jg < NN){ sSx[tid]=sxA[jg]; sSy[tid]=syA[jg]; sC[tid]=cjA[jg]; }
    else        { sSx[tid]=0.f; sSy[tid]=0.f; sC[tid]=-3e38f; }
  }

  float acc[4][8];
  #pragma unroll
  for (int i=0;i<4;i++)
    #pragma unroll
    for (int j=0;j<8;j++) acc[i][j] = 0.f;

  for (int kt = 0; kt < 8; kt++){
    const int k0 = kt << 5;
    __syncthreads();
    #pragma unroll
    for (int c=0;c<2;c++){
      int lin = tid + c*256;            // 0..511: A, 64 rows x 8 float4
      int row = lin >> 3, c4 = (lin & 7) << 2;
      int gm = m0 + row;
      float4 v = make_float4(0.f,0.f,0.f,0.f);
      if (gm < NN) v = *(const float4*)(Z + (size_t)gm*256 + k0 + c4);
      *(float4*)&lA[row][c4] = v;
    }
    #pragma unroll
    for (int c=0;c<4;c++){
      int lin = tid + c*256;            // 0..1023: B, 128 rows x 8 float4
      int row = lin >> 3, c4 = (lin & 7) << 2;
      int gn = n0 + row;
      float4 v = make_float4(0.f,0.f,0.f,0.f);
      if (gn < NN) v = *(const float4*)(Znb + (size_t)gn*256 + k0 + c4);
      *(float4*)&lB[row][c4] = v;
    }
    __syncthreads();
    #pragma unroll 2
    for (int kk=0; kk<32; kk+=4){
      float4 a[4], b[8];
      #pragma unroll
      for (int i=0;i<4;i++) a[i] = *(const float4*)&lA[ty+16*i][kk];
      #pragma unroll
      for (int j=0;j<8;j++) b[j] = *(const float4*)&lB[tx+16*j][kk];
      #pragma unroll
      for (int u=0;u<4;u++){
        #pragma unroll
        for (int i=0;i<4;i++){
          float av = (&a[i].x)[u];
          #pragma unroll
          for (int j=0;j<8;j++)
            acc[i][j] += av * (&b[j].x)[u];
        }
      }
    }
  }

  __syncthreads();
  #pragma unroll
  for (int i=0;i<4;i++)
    #pragma unroll
    for (int j=0;j<8;j++)
      stile[ty+16*i][tx+16*j] = acc[i][j];
  __syncthreads();

  if (tid < 64){
    const int gi = m0 + tid;
    if (gi < NN){
      float sxi = sxA[gi], syi = syA[gi];
      float tv[NCAND]; int ti[NCAND];
      #pragma unroll
      for (int p=0;p<NCAND;p++){ tv[p] = -3.4e38f; ti[p] = -1; }
      #pragma unroll 1
      for (int jj=0; jj<128; jj++){
        float s = 2.f*stile[tid][jj] + 2.f*(sxi*sSx[jj] + syi*sSy[jj]) + sC[jj];
        if (s > tv[NCAND-1]){
          bool g[NCAND];
          #pragma unroll
          for (int p=0;p<NCAND;p++) g[p] = s > tv[p];
          #pragma unroll
          for (int p=NCAND-1;p>0;--p) if (g[p-1]){ tv[p]=tv[p-1]; ti[p]=ti[p-1]; }
          #pragma unroll
          for (int p=0;p<NCAND;p++){ bool pl = g[p] && (p==0 || !g[p-1]); if (pl){ tv[p]=s; ti[p]=n0+jj; } }
        }
      }
      size_t base = ((size_t)gi*NTILE + blockIdx.x)*NCAND;
      #pragma unroll
      for (int p=0;p<NCAND;p++){ candV[base+p]=tv[p]; candI[base+p]=ti[p]; }
    }
  }
}

// ---------------- merge: f32 prefilter -> f64 wave rescore -> top-9 ---------
__global__ __launch_bounds__(256)
void merge64_k(const float* __restrict__ candV, const int* __restrict__ candI,
               const double* __restrict__ Z, const double* __restrict__ Znb,
               const double* __restrict__ sx64, const double* __restrict__ sy64,
               double* __restrict__ wgt9, int* __restrict__ idx9)
{
  __shared__ double zi[256];
  __shared__ float  fv[TCAND];
  __shared__ int    fj[TCAND];
  __shared__ float  tvs[PRE];
  __shared__ int    pj[PRE];
  __shared__ double ps[PRE];
  __shared__ double tv9[9];
  __shared__ int    ti9[9];

  const int i = blockIdx.x;
  const int t = threadIdx.x;
  zi[t] = Z[(size_t)i*256 + t];
  for (int c = t; c < TCAND; c += 256){
    fv[c] = candV[(size_t)i*TCAND + c];
    fj[c] = candI[(size_t)i*TCAND + c];
  }
  __syncthreads();

  if (t == 0){
    for (int p=0;p<PRE;p++){ tvs[p]=-3.4e38f; pj[p]=-1; }
    for (int c=0;c<TCAND;c++){
      float s = fv[c];
      if (!(s > tvs[PRE-1])) continue;
      int j = fj[c];
      if (j < 0) continue;
      int p = PRE-1;
      while (p > 0 && s > tvs[p-1]){ tvs[p]=tvs[p-1]; pj[p]=pj[p-1]; --p; }
      tvs[p]=s; pj[p]=j;
    }
  }
  __syncthreads();

  const int wv = t >> 6, lane = t & 63;
  const double sxi = sx64[i], syi = sy64[i];
  for (int c = wv; c < PRE; c += 4){
    int j = pj[c];
    double s = -1.0e300;
    if (j >= 0){
      const double* zj = Znb + (size_t)j*256;
      double p = 0.0;
      #pragma unroll
      for (int u=0;u<4;u++){
        double b = zj[lane + 64*u];
        double a = zi[lane + 64*u];
        p = fma(2.0*a - b, b, p);     // += 2ab - b^2
      }
      #pragma unroll
      for (int off=32; off; off>>=1) p += __shfl_xor(p, off);
      double sxj = sx64[j], syj = sy64[j];
      s = p + 2.0*(sxi*sxj + syi*syj) - (sxj*sxj + syj*syj);
    }
    if (lane == 0) ps[c] = s;
  }
  __syncthreads();

  if (t == 0){
    for (int p=0;p<9;p++){ tv9[p]=-1.0e301; ti9[p]=0x7FFFFFFF; }
    for (int c=0;c<PRE;c++){
      double s = ps[c]; int j = pj[c];
      if (j < 0 || s < -1.0e299) continue;
      if (!((s > tv9[8]) || (s == tv9[8] && j < ti9[8]))) continue;
      int p = 8;
      while (p > 0 && ((s > tv9[p-1]) || (s == tv9[p-1] && j < ti9[p-1]))){
        tv9[p]=tv9[p-1]; ti9[p]=ti9[p-1]; --p;
      }
      tv9[p]=s; ti9[p]=j;
    }
    double m = tv9[0], e[9], S=0.0;
    for (int k=0;k<9;k++){ e[k]=exp(tv9[k]-m); S+=e[k]; }
    for (int k=0;k<9;k++){
      wgt9[(size_t)i*9+k] = e[k]/S;
      idx9[(size_t)i*9+k] = ti9[k];
    }
  }
}

// ---------------- znb prep + casts ------------------------------------------
__global__ __launch_bounds__(256)
void znbprep_k(const double* __restrict__ znb, const double* __restrict__ ssq64,
               float* __restrict__ cjA)
{
  __shared__ double red[256];
  int i = blockIdx.x, d = threadIdx.x;
  double v = znb[(size_t)i*256 + d];
  red[d] = v*v;
  __syncthreads();
  for (int s=128; s; s>>=1){ if (d<s) red[d]+=red[d+s]; __syncthreads(); }
  if (d==0) cjA[i] = -(float)(red[0] + ssq64[i]);
}
__global__ void castz_k(const double* __restrict__ z64, float* __restrict__ z32, int n){
  int t = blockIdx.x*256+threadIdx.x;
  if (t < n) z32[t] = (float)z64[t];
}
__global__ void featout_k(const double* __restrict__ z, float* __restrict__ o){
  int t = blockIdx.x*256+threadIdx.x;
  if (t < NN*128){ int i=t>>7, d=t&127; o[t] = (float)z[(size_t)i*256 + d]; }
}

__global__ __launch_bounds__(256)
void zout_k(const double* __restrict__ Z, const double* __restrict__ Znb,
            const int* __restrict__ idx9, const double* __restrict__ wgt9,
            float* __restrict__ zoOut, float* __restrict__ zoF32, float* __restrict__ x1)
{
  int i = blockIdx.x; int d = threadIdx.x;
  double a = Z[(size_t)i*256 + d];
  #pragma unroll
  for (int k=0;k<9;k++){
    int j = idx9[(size_t)i*9+k];
    double w = wgt9[(size_t)i*9+k];
    double t = w * Znb[(size_t)j*256 + d];
    a += t;
    x1[((size_t)i*9+k)*256 + d] = (float)t;
  }
  float af = (float)a;
  zoOut[(size_t)i*256+d] = af;
  zoF32[(size_t)i*256+d] = af;
}

__global__ __launch_bounds__(256)
void q_k(const float* __restrict__ zoF, const float* __restrict__ clus, float* __restrict__ qB)
{
  __shared__ float wred[10][4];
  __shared__ float qs[10];
  int i = blockIdx.x, d = threadIdx.x;
  int lane = d & 63, wv = d >> 6;
  float zo = zoF[(size_t)i*256 + d];
  #pragma unroll
  for (int c=0;c<10;c++){
    float df = zo - clus[(size_t)c*256 + d];
    float p = df*df;
    #pragma unroll
    for (int off=32; off; off>>=1) p += __shfl_down(p, off);
    if (lane == 0) wred[c][wv] = p;
  }
  __syncthreads();
  if (d < 10){
    float d2 = wred[d][0]+wred[d][1]+wred[d][2]+wred[d][3];
    qs[d] = 1.f/(1.f + d2);
  }
  __syncthreads();
  if (d < 10){
    float s = 0.f;
    #pragma unroll
    for (int c=0;c<10;c++) s += qs[c];
    qB[(size_t)i*10 + d] = qs[d]/s;
  }
}

// ---------------- host ------------------------------------------------------
extern "C" void kernel_launch(void* const* d_in, const int* in_sizes, int n_in,
                              void* d_out, int out_size, void* d_ws, size_t ws_size,
                              hipStream_t stream)
{
  (void)in_sizes; (void)n_in; (void)out_size; (void)ws_size;
  const float* x    = (const float*)d_in[0];
  const float* xnb  = (const float*)d_in[1];
  const float* spat = (const float*)d_in[2];
  const int*   adj  = (const int*)d_in[3];
  const int*   adjp = (const int*)d_in[4];
  const float* W1   = (const float*)d_in[5];
  const float* b1   = (const float*)d_in[6];
  const float* g1   = (const float*)d_in[7];
  const float* be1  = (const float*)d_in[8];
  const float* W2   = (const float*)d_in[9];
  const float* b2   = (const float*)d_in[10];
  const float* g2   = (const float*)d_in[11];
  const float* be2  = (const float*)d_in[12];
  const float* Wq   = (const float*)d_in[13];
  const float* Wk   = (const float*)d_in[14];
  const float* Wv   = (const float*)d_in[15];
  const float* Wsm  = (const float*)d_in[16];
  const float* bq   = (const float*)d_in[17];
  const float* bk   = (const float*)d_in[18];
  const float* bv   = (const float*)d_in[19];
  const float* bs   = (const float*)d_in[20];
  const float* decW = (const float*)d_in[21];
  const float* decb = (const float*)d_in[22];
  const float* decg = (const float*)d_in[23];
  const float* decbe= (const float*)d_in[24];
  const float* clus = (const float*)d_in[25];
  float* outF = (float*)d_out;
  const int* srcA = adj,  *dstA = adj + NE;
  const int* srcP = adjp, *dstP = adjp + NE;

  char* wsb = (char*)d_ws;
  size_t off = 0;
  auto alloc = [&](size_t bytes)->char*{
    char* p = wsb + off;
    off = (off + bytes + 255) & ~(size_t)255;
    return p;
  };
  double* W1t  = (double*)alloc(768000*8);
  double* W2t  = (double*)alloc(32768*8);
  double* Bct  = (double*)alloc(196608*8);
  float*  Dt   = (float*) alloc(768000*4);
  double* bcat = (double*)alloc(1536*8);
  double* sx64 = (double*)alloc(NN*8);
  double* sy64 = (double*)alloc(NN*8);
  double* ssq64= (double*)alloc(NN*8);
  float*  sx32 = (float*) alloc(NN*4);
  float*  sy32 = (float*) alloc(NN*4);
  double* b1c  = (double*)alloc(256*8);
  double* b2c  = (double*)alloc(128*8);
  double* H1   = (double*)alloc((size_t)NN*256*8);
  double* zX64 = (double*)alloc((size_t)NN*256*8);
  double* zNB64= (double*)alloc((size_t)NN*256*8);
  double* hcur = (double*)alloc((size_t)NN*128*8);
  double* QK1  = (double*)alloc((size_t)NN*512*8);
  double* QK2  = (double*)alloc((size_t)NN*512*8);
  double* alphaA=(double*)alloc((size_t)NE*8);
  double* alphaP=(double*)alloc((size_t)NE*8);
  double* part = (double*)alloc((size_t)4*NN*256*8);   // split-K partials (49 MB)
  // CSRs
  int* rpDA = (int*)alloc((NN+1)*4);
  int* rpDP = (int*)alloc((NN+1)*4);
  int* rpSA = (int*)alloc((NN+1)*4);
  int* rpSP = (int*)alloc((NN+1)*4);
  int* curDA= (int*)alloc(NN*4);
  int* curDP= (int*)alloc(NN*4);
  int* curSA= (int*)alloc(NN*4);
  int* curSP= (int*)alloc(NN*4);
  int* elDA = (int*)alloc(NE*4);
  int* elDP = (int*)alloc(NE*4);
  int* elSA = (int*)alloc(NE*4);
  int* elSP = (int*)alloc(NE*4);
  float*  zX32 = (float*) alloc((size_t)NN*256*4);
  float*  zNB32= (float*) alloc((size_t)NN*256*4);
  float*  cjA  = (float*) alloc(NN*4);
  float*  candV= (float*) alloc((size_t)NN*TCAND*4);
  int*    candI= (int*)   alloc((size_t)NN*TCAND*4);
  int*    idx9 = (int*)   alloc((size_t)NN*9*4);
  double* wgt9 = (double*)alloc((size_t)NN*9*8);
  float*  zoF32= (float*) alloc((size_t)NN*256*4);

  prep_k<<<6926, 256, 0, stream>>>(W1, W2, Wq, Wk, Wv, Wsm, bq, bk, bv, bs, decW, spat,
                                   W1t, W2t, Bct, Dt, bcat,
                                   sx64, sy64, ssq64, sx32, sy32);
  castup_k<<<1, 256, 0, stream>>>(b1, b1c, 256);
  castup_k<<<1, 256, 0, stream>>>(b2, b2c, 128);

  // CSR build (4 CSRs)
  hipMemsetAsync(curDA, 0, NN*4, stream);
  hipMemsetAsync(curDP, 0, NN*4, stream);
  hipMemsetAsync(curSA, 0, NN*4, stream);
  hipMemsetAsync(curSP, 0, NN*4, stream);
  csr_cnt_k<<<375, 256, 0, stream>>>(dstA, curDA);
  csr_cnt_k<<<375, 256, 0, stream>>>(dstP, curDP);
  csr_cnt_k<<<375, 256, 0, stream>>>(srcA, curSA);
  csr_cnt_k<<<375, 256, 0, stream>>>(srcP, curSP);
  csr_scan_k<<<1, 256, 0, stream>>>(curDA, rpDA, curDA);
  csr_scan_k<<<1, 256, 0, stream>>>(curDP, rpDP, curDP);
  csr_scan_k<<<1, 256, 0, stream>>>(curSA, rpSA, curSA);
  csr_scan_k<<<1, 256, 0, stream>>>(curSP, rpSP, curSP);
  csr_fill_k<<<375, 256, 0, stream>>>(dstA, curDA, elDA);
  csr_fill_k<<<375, 256, 0, stream>>>(dstP, curDP, elDP);
  csr_fill_k<<<375, 256, 0, stream>>>(srcA, curSA, elSA);
  csr_fill_k<<<375, 256, 0, stream>>>(srcP, curSP, elSP);

  auto enc = [&](const float* xin, double* zbuf, bool isX){
    gemm64s_k<float><<<dim3(4,94,4), 256, 0, stream>>>(xin, KDIN, W1t, KDIN,
                                                       NN, KDIN, 768, 256, part);
    epi64_k<<<(NN*256+255)/256, 256, 0, stream>>>(part, 4, (size_t)NN*256,
                                                  NN, 256, b1c, g1, be1, H1, 256);
    gemm64s_k<double><<<dim3(2,94,4), 256, 0, stream>>>(H1, 256, W2t, 256,
                                                        NN, 256, 64, 128, part);
    epi64_k<<<(NN*128+255)/256, 256, 0, stream>>>(part, 4, (size_t)NN*128,
                                                  NN, 128, b2c, g2, be2, zbuf, 256);
    const double* hin = zbuf; int ldh = 256;
    for (int l=0; l<3; l++){
      const double* Bh = Bct + (size_t)l*65536;
      const double* bc = bcat + l*512;
      if (l != 1){
        gemm64_k<0,double><<<dim3(8,94), 256, 0, stream>>>(hin, ldh, Bh, 128, NN, 128, 512,
                                                           QK1, 512, bc, nullptr, nullptr, QK2);
        attn_k<<<1500, 256, 0, stream>>>(QK1, rpDA, elDA, srcA, alphaA);
        attn_k<<<1500, 256, 0, stream>>>(QK2, rpDP, elDP, srcP, alphaP);
      } else {
        gemm64_k<0,double><<<dim3(8,94), 256, 0, stream>>>(hin, ldh, Bh, 128, NN, 128, 512,
                                                           QK1, 512, bc, nullptr, nullptr, nullptr);
        attn_k<<<1500, 256, 0, stream>>>(QK1, rpDA, elDA, srcA, alphaA);
        gemm64_k<0,double><<<dim3(8,94), 256, 0, stream>>>(QK1 + 384, 512, Bh, 128, NN, 128, 512,
                                                           QK2, 512, bc, nullptr, nullptr, nullptr);
        attn_k<<<1500, 256, 0, stream>>>(QK2, rpDP, elDP, srcP, alphaP);
      }
      if (isX && l == 2){
        hipMemsetAsync(outF + (size_t)OFF_ATT, 0, (size_t)NN*NN*4, stream);
        att_scatter_k<<<375, 256, 0, stream>>>(srcP, dstP, alphaP, outF + (size_t)OFF_ATT);
      }
      if (l < 2){
        spmm_csr_k<<<1500, 256, 0, stream>>>(QK1, QK2, rpSA, elSA, dstA, alphaA,
                                             rpSP, elSP, dstP, alphaP, hcur, 128, 0, 1);
        hin = hcur; ldh = 128;
      } else {
        spmm_csr_k<<<1500, 256, 0, stream>>>(QK1, QK2, rpSA, elSA, dstA, alphaA,
                                             rpSP, elSP, dstP, alphaP, zbuf, 256, 128, 0);
      }
    }
  };
  enc(x,   zX64,  true);
  enc(xnb, zNB64, false);

  castz_k<<<6000, 256, 0, stream>>>(zX64,  zX32,  NN*256);
  castz_k<<<6000, 256, 0, stream>>>(zNB64, zNB32, NN*256);
  znbprep_k<<<NN, 256, 0, stream>>>(zNB64, ssq64, cjA);
  dist32_k<<<dim3(NTILE,94), 256, 0, stream>>>(zX32, zNB32, sx32, sy32, cjA, candV, candI);
  merge64_k<<<NN, 256, 0, stream>>>(candV, candI, zX64, zNB64, sx64, sy64, wgt9, idx9);

  zout_k<<<NN, 256, 0, stream>>>(zX64, zNB64, idx9, wgt9,
                                 outF + (size_t)OFF_ZOUT, zoF32, outF + (size_t)OFF_X1);
  gemm32d_k<<<dim3(47,94), 256, 0, stream>>>(zoF32, 256, Dt, 256, NN, 256, 3000,
                                             outF + (size_t)OFF_DE1, 3000, decb, decg, decbe,
                                             outF + (size_t)OFF_DE2);
  q_k<<<NN, 256, 0, stream>>>(zoF32, clus, outF + (size_t)OFF_Q);
  featout_k<<<3000, 256, 0, stream>>>(zX64, outF + (size_t)OFF_FEAT);
}